// Round 2
// baseline (1058.680 us; speedup 1.0000x reference)
//
#include <hip/hip_runtime.h>

#define NN 131072   // nodes
#define EE 262144   // edges
#define GG 4096     // graphs

__global__ void k_fill(float* p, int n, float v) {
    int i = blockIdx.x * 256 + threadIdx.x;
    if (i < n) p[i] = v;
}

__global__ void k_count(const int* dst, float* deg) {
    int e = blockIdx.x * 256 + threadIdx.x;
    if (e < EE) atomicAdd(&deg[dst[e]], 1.0f);
}

__global__ void k_rsqrt(float* deg) {
    int i = blockIdx.x * 256 + threadIdx.x;
    if (i < NN) deg[i] = rsqrtf(deg[i]);
}

// agg1[i][j] = x[i]*W1[j]*dinv[i]^2 + b1[j]   (conv1 self-loop + bias, h1 never materialized)
__global__ void k_init1(const float* x, const float* dinv, const float* W1, const float* b1,
                        float* agg1) {
    int idx = blockIdx.x * 256 + threadIdx.x;   // N*16 threads, float4 each
    if (idx < NN * 16) {
        int i = idx >> 4, q = idx & 15;
        float s = x[i] * dinv[i] * dinv[i];
        const float4 w = *(const float4*)&W1[q * 4];
        const float4 b = *(const float4*)&b1[q * 4];
        float4 o;
        o.x = s * w.x + b.x; o.y = s * w.y + b.y;
        o.z = s * w.z + b.z; o.w = s * w.w + b.w;
        *(float4*)&agg1[(size_t)i * 64 + q * 4] = o;
    }
}

// conv1 edge scatter: agg1[d][j] += x[s]*W1[j] * dinv[s]*dinv[d]
__global__ void k_scatter1(const int* src, const int* dst, const float* dinv,
                           const float* x, const float* W1, float* agg1) {
    int t = blockIdx.x * 256 + threadIdx.x;   // E*64
    if (t < EE * 64) {
        int e = t >> 6, j = t & 63;
        int s = src[e], d = dst[e];
        float coef = x[s] * dinv[s] * dinv[d];
        atomicAdd(&agg1[d * 64 + j], coef * W1[j]);
    }
}

// agg[dst] += h[src] * dinv[src]*dinv[dst]
template <int C>
__global__ void k_scatter(const int* src, const int* dst, const float* dinv,
                          const float* h, float* agg) {
    int t = blockIdx.x * 256 + threadIdx.x;
    if (t < EE * C) {
        int e = t / C, j = t % C;
        int s = src[e], d = dst[e];
        float coef = dinv[s] * dinv[d];
        atomicAdd(&agg[d * C + j], h[s * C + j] * coef);
    }
}

// Register-tiled fp32 GEMM: C[N,OUTW] = relu(A[N,K]) @ W[K,OUTW]
// BM=64, BN=128, KC=64; 256 threads; each thread owns a 4x8 register tile.
// FUSE3=false: write H and AGG = H*dinv^2 + bias  (conv2)
// FUSE3=true : write H and atomicAdd pooled[batch[i]*256+j] += H*dinv^2 + bias  (conv3)
template <int K, int OUTW, bool FUSE3>
__global__ __launch_bounds__(256) void k_mm(const float* __restrict__ A,
                                            const float* __restrict__ W,
                                            const float* __restrict__ bias,
                                            const float* __restrict__ dinv,
                                            const int* __restrict__ batch,
                                            float* __restrict__ H,
                                            float* __restrict__ AGGP) {
    const int BM = 64, BN = 128, KC = 64;
    __shared__ float At[BM][KC + 4];   // +4 pad keeps 16B alignment, 2-way max on writes
    __shared__ float Wt[KC][BN];

    int tid  = threadIdx.x;
    int colg = tid & 15;    // 16 col groups * 8 cols (split 4+4)
    int rowg = tid >> 4;    // 16 row groups * 4 rows
    int i0 = blockIdx.x * BM;
    int j0 = blockIdx.y * BN;

    float acc[4][8];
#pragma unroll
    for (int r = 0; r < 4; ++r)
#pragma unroll
        for (int c = 0; c < 8; ++c) acc[r][c] = 0.0f;

    for (int k0 = 0; k0 < K; k0 += KC) {
        __syncthreads();
        // A tile (relu applied): rows i0..i0+63, cols k0..k0+63
        {
            int k4 = tid & 15, r0 = tid >> 4;
#pragma unroll
            for (int p = 0; p < 4; ++p) {
                int r = r0 + p * 16;
                const float4 v = *(const float4*)&A[(size_t)(i0 + r) * K + k0 + k4 * 4];
                float4 rv;
                rv.x = fmaxf(v.x, 0.f); rv.y = fmaxf(v.y, 0.f);
                rv.z = fmaxf(v.z, 0.f); rv.w = fmaxf(v.w, 0.f);
                *(float4*)&At[r][k4 * 4] = rv;
            }
        }
        // W tile: rows k0..k0+63, cols j0..j0+127
        {
            int c4 = tid & 31, kk0 = tid >> 5;
#pragma unroll
            for (int p = 0; p < 8; ++p) {
                int kk = kk0 + p * 8;
                *(float4*)&Wt[kk][c4 * 4] =
                    *(const float4*)&W[(size_t)(k0 + kk) * OUTW + j0 + c4 * 4];
            }
        }
        __syncthreads();
#pragma unroll 4
        for (int kk = 0; kk < KC; ++kk) {
            float a[4];
#pragma unroll
            for (int r = 0; r < 4; ++r) a[r] = At[rowg * 4 + r][kk];
            const float4 w0 = *(const float4*)&Wt[kk][colg * 4];
            const float4 w1 = *(const float4*)&Wt[kk][64 + colg * 4];
            float w[8] = {w0.x, w0.y, w0.z, w0.w, w1.x, w1.y, w1.z, w1.w};
#pragma unroll
            for (int r = 0; r < 4; ++r)
#pragma unroll
                for (int c = 0; c < 8; ++c) acc[r][c] += a[r] * w[c];
        }
    }

    // epilogue
#pragma unroll
    for (int r = 0; r < 4; ++r) {
        int i = i0 + rowg * 4 + r;
        float di = dinv[i];
        float d2 = di * di;
#pragma unroll
        for (int h = 0; h < 2; ++h) {
            int j = j0 + h * 64 + colg * 4;
            float4 v;
            v.x = acc[r][h * 4 + 0]; v.y = acc[r][h * 4 + 1];
            v.z = acc[r][h * 4 + 2]; v.w = acc[r][h * 4 + 3];
            *(float4*)&H[(size_t)i * OUTW + j] = v;
            const float4 b = *(const float4*)&bias[j];
            if (!FUSE3) {
                float4 o;
                o.x = v.x * d2 + b.x; o.y = v.y * d2 + b.y;
                o.z = v.z * d2 + b.z; o.w = v.w * d2 + b.w;
                *(float4*)&AGGP[(size_t)i * OUTW + j] = o;
            } else {
                float* pg = &AGGP[(size_t)batch[i] * 256 + j];
                atomicAdd(pg + 0, v.x * d2 + b.x);
                atomicAdd(pg + 1, v.y * d2 + b.y);
                atomicAdd(pg + 2, v.z * d2 + b.z);
                atomicAdd(pg + 3, v.w * d2 + b.w);
            }
        }
    }
}

// conv3 edge contributions scattered straight into per-graph pooled sums
__global__ void k_scatter_pool(const int* src, const int* dst, const float* dinv,
                               const int* batch, const float* h3, float* pooled) {
    long t = (long)blockIdx.x * 256 + threadIdx.x;  // E*256
    if (t < (long)EE * 256) {
        int e = (int)(t >> 8), c = (int)(t & 255);
        int s = src[e], d = dst[e];
        float coef = dinv[s] * dinv[d];
        atomicAdd(&pooled[(size_t)batch[d] * 256 + c], h3[(size_t)s * 256 + c] * coef);
    }
}

__global__ void k_cnt(const int* batch, float* cnt) {
    int i = blockIdx.x * 256 + threadIdx.x;
    if (i < NN) atomicAdd(&cnt[batch[i]], 1.0f);
}

// per-graph head: mean -> fc1+relu -> fc2
__global__ __launch_bounds__(128) void k_head(const float* pooled, const float* cnt,
                                              const float* fc1W, const float* fc1b,
                                              const float* fc2W, const float* fc2b,
                                              float* out) {
    __shared__ float mean[256];
    __shared__ float g1[128];
    int g = blockIdx.x, t = threadIdx.x;
    float inv = 1.0f / fmaxf(cnt[g], 1.0f);
    mean[t]       = pooled[g * 256 + t]       * inv;
    mean[t + 128] = pooled[g * 256 + 128 + t] * inv;
    __syncthreads();
    float acc = fc1b[t];
    for (int j = 0; j < 256; ++j) acc += mean[j] * fc1W[j * 128 + t];
    g1[t] = fmaxf(acc, 0.0f);
    __syncthreads();
    if (t < 12) {
        float o = fc2b[t];
        for (int k = 0; k < 128; ++k) o += g1[k] * fc2W[k * 12 + t];
        out[g * 12 + t] = o;
    }
}

extern "C" void kernel_launch(void* const* d_in, const int* in_sizes, int n_in,
                              void* d_out, int out_size, void* d_ws, size_t ws_size,
                              hipStream_t stream) {
    const float* x     = (const float*)d_in[0];
    const int*   ei    = (const int*)d_in[1];
    const int*   batch = (const int*)d_in[2];
    const float* W1    = (const float*)d_in[3];
    const float* b1    = (const float*)d_in[4];
    const float* W2    = (const float*)d_in[5];
    const float* b2    = (const float*)d_in[6];
    const float* W3    = (const float*)d_in[7];
    const float* b3    = (const float*)d_in[8];
    const float* fc1W  = (const float*)d_in[9];
    const float* fc1b  = (const float*)d_in[10];
    const float* fc2W  = (const float*)d_in[11];
    const float* fc2b  = (const float*)d_in[12];
    float* out = (float*)d_out;

    const int* srcp = ei;        // edge_index[0]
    const int* dstp = ei + EE;   // edge_index[1]

    // workspace layout (peak ~206 MB, same as R1):
    //   dinv   : N
    //   regA   : N*256 floats — holds agg1 (N*64) then h2 (N*128, offset N*64);
    //            later reused wholesale as h3 (N*256) once scatter2 is done
    //   agg2   : N*128
    //   pooled : G*256 ; cnt : G
    float* ws     = (float*)d_ws;
    float* dinv   = ws;
    float* regA   = dinv + NN;
    float* agg1   = regA;                        // N*64
    float* h2     = regA + (size_t)NN * 64;      // N*128
    float* h3     = regA;                        // N*256 (after scatter2)
    float* agg2   = regA + (size_t)NN * 256;     // N*128
    float* pooled = agg2 + (size_t)NN * 128;     // G*256
    float* cnt    = pooled + (size_t)GG * 256;   // G

    // degree + rsqrt ; zero pooled+cnt
    k_fill<<<(NN + 255) / 256, 256, 0, stream>>>(dinv, NN, 1.0f);
    k_fill<<<(GG * 256 + GG + 255) / 256, 256, 0, stream>>>(pooled, GG * 256 + GG, 0.0f);
    k_count<<<EE / 256, 256, 0, stream>>>(dstp, dinv);
    k_rsqrt<<<NN / 256, 256, 0, stream>>>(dinv);

    // conv1 (h1 never materialized)
    k_init1<<<NN * 16 / 256, 256, 0, stream>>>(x, dinv, W1, b1, agg1);
    k_scatter1<<<EE * 64 / 256, 256, 0, stream>>>(srcp, dstp, dinv, x, W1, agg1);

    // conv2: h2 = relu(agg1)@W2 ; agg2 base fused into epilogue; then edge scatter
    k_mm<64, 128, false><<<dim3(NN / 64, 1), 256, 0, stream>>>(
        agg1, W2, b2, dinv, nullptr, h2, agg2);
    k_scatter<128><<<EE * 128 / 256, 256, 0, stream>>>(srcp, dstp, dinv, h2, agg2);

    // conv3: h3 = relu(agg2)@W3 ; self-loop+bias pooled in epilogue; edge scatter to pool
    k_mm<128, 256, true><<<dim3(NN / 64, 2), 256, 0, stream>>>(
        agg2, W3, b3, dinv, batch, h3, pooled);
    k_scatter_pool<<<EE, 256, 0, stream>>>(srcp, dstp, dinv, batch, h3, pooled);
    k_cnt<<<NN / 256, 256, 0, stream>>>(batch, cnt);

    // head
    k_head<<<GG, 128, 0, stream>>>(pooled, cnt, fc1W, fc1b, fc2W, fc2b, out);
}

// Round 3
// 358.104 us; speedup vs baseline: 2.9563x; 2.9563x over previous
//
#include <hip/hip_runtime.h>

#define NN 131072   // nodes
#define EE 262144   // edges
#define GG 4096     // graphs

// ---------- CSR build ----------
__global__ void k_count(const int* __restrict__ dst, int* __restrict__ indeg) {
    int e = blockIdx.x * 256 + threadIdx.x;
    if (e < EE) atomicAdd(&indeg[dst[e]], 1);
}

__global__ void k_dinv(const int* __restrict__ indeg, float* __restrict__ dinv) {
    int i = blockIdx.x * 256 + threadIdx.x;
    if (i < NN) dinv[i] = rsqrtf((float)indeg[i] + 1.0f);
}

// exclusive scan of indeg[N] -> rowptr[N+1], single block of 1024 threads, 128 elems each
__global__ __launch_bounds__(1024) void k_scan(const int* __restrict__ indeg,
                                               int* __restrict__ rowptr) {
    __shared__ int ps[1024];
    int tid = threadIdx.x;
    int base = tid * 128;
    int s = 0;
    for (int j = 0; j < 128; ++j) s += indeg[base + j];
    ps[tid] = s;
    __syncthreads();
    for (int off = 1; off < 1024; off <<= 1) {
        int v = (tid >= off) ? ps[tid - off] : 0;
        __syncthreads();
        ps[tid] += v;
        __syncthreads();
    }
    int run = (tid > 0) ? ps[tid - 1] : 0;
    for (int j = 0; j < 128; ++j) {
        rowptr[base + j] = run;
        run += indeg[base + j];
    }
    if (tid == 1023) rowptr[NN] = run;
}

__global__ void k_fill_edges(const int* __restrict__ src, const int* __restrict__ dst,
                             int* __restrict__ cursor, int* __restrict__ ecol) {
    int e = blockIdx.x * 256 + threadIdx.x;
    if (e < EE) {
        int d = dst[e];
        int slot = atomicAdd(&cursor[d], 1);
        ecol[slot] = src[e];
    }
}

// ---------- conv1 scalar: z[i] = dinv_i * sum_in(x_s*dinv_s) + x_i*dinv_i^2 ----------
__global__ void k_z(const float* __restrict__ x, const float* __restrict__ dinv,
                    const int* __restrict__ rowptr, const int* __restrict__ ecol,
                    float* __restrict__ z) {
    int i = blockIdx.x * 256 + threadIdx.x;
    if (i < NN) {
        float s = 0.0f;
        int e0 = rowptr[i], e1 = rowptr[i + 1];
        for (int e = e0; e < e1; ++e) {
            int sn = ecol[e];
            s += x[sn] * dinv[sn];
        }
        float di = dinv[i];
        z[i] = di * (s + x[i] * di);
    }
}

// ---------- register-tiled fp32 GEMM: H = relu(A) @ W  (or A generated from z,W1,b1) ----------
// BM=64, BN=128, KC=64; 256 threads; 4x8 register tile per thread.
template <int K, int OUTW, bool GENA>
__global__ __launch_bounds__(256) void k_mm(const float* __restrict__ A,
                                            const float* __restrict__ zv,
                                            const float* __restrict__ W1,
                                            const float* __restrict__ b1,
                                            const float* __restrict__ W,
                                            float* __restrict__ H) {
    __shared__ float At[64][68];     // [row][k], +4 pad keeps 16B alignment
    __shared__ float Wt[64][128];    // [k][col]
    __shared__ float zs[64], w1s[64], b1s[64];

    int tid  = threadIdx.x;
    int colg = tid & 15;    // 16 col groups x 8 cols (4+4 split)
    int rowg = tid >> 4;    // 16 row groups x 4 rows
    int i0 = blockIdx.x * 64;
    int j0 = blockIdx.y * 128;

    float acc[4][8];
#pragma unroll
    for (int r = 0; r < 4; ++r)
#pragma unroll
        for (int c = 0; c < 8; ++c) acc[r][c] = 0.0f;

    for (int k0 = 0; k0 < K; k0 += 64) {
        __syncthreads();
        if constexpr (GENA) {
            // A-tile = relu(z[i]*W1[k] + b1[k]) generated on the fly (K==64)
            if (tid < 64) { zs[tid] = zv[i0 + tid]; w1s[tid] = W1[tid]; b1s[tid] = b1[tid]; }
            __syncthreads();
#pragma unroll
            for (int p = 0; p < 16; ++p) {
                int idx = tid + p * 256;
                int k = idx & 63, r = idx >> 6;
                At[r][k] = fmaxf(zs[r] * w1s[k] + b1s[k], 0.0f);
            }
        } else {
            int k4 = tid & 15, r0 = tid >> 4;
#pragma unroll
            for (int p = 0; p < 4; ++p) {
                int r = r0 + p * 16;
                const float4 v = *(const float4*)&A[(size_t)(i0 + r) * K + k0 + k4 * 4];
                float4 rv;
                rv.x = fmaxf(v.x, 0.f); rv.y = fmaxf(v.y, 0.f);
                rv.z = fmaxf(v.z, 0.f); rv.w = fmaxf(v.w, 0.f);
                *(float4*)&At[r][k4 * 4] = rv;
            }
        }
        {
            int c4 = tid & 31, kk0 = tid >> 5;
#pragma unroll
            for (int p = 0; p < 8; ++p) {
                int kk = kk0 + p * 8;
                *(float4*)&Wt[kk][c4 * 4] =
                    *(const float4*)&W[(size_t)(k0 + kk) * OUTW + j0 + c4 * 4];
            }
        }
        __syncthreads();
#pragma unroll 4
        for (int kk = 0; kk < 64; ++kk) {
            float a[4];
#pragma unroll
            for (int r = 0; r < 4; ++r) a[r] = At[rowg * 4 + r][kk];  // 16-way broadcast b32
            const float4 w0 = *(const float4*)&Wt[kk][colg * 4];
            const float4 w1 = *(const float4*)&Wt[kk][64 + colg * 4];
            float w[8] = {w0.x, w0.y, w0.z, w0.w, w1.x, w1.y, w1.z, w1.w};
#pragma unroll
            for (int r = 0; r < 4; ++r)
#pragma unroll
                for (int c = 0; c < 8; ++c) acc[r][c] += a[r] * w[c];
        }
    }

#pragma unroll
    for (int r = 0; r < 4; ++r) {
        int i = i0 + rowg * 4 + r;
#pragma unroll
        for (int h = 0; h < 2; ++h) {
            float4 v;
            v.x = acc[r][h * 4 + 0]; v.y = acc[r][h * 4 + 1];
            v.z = acc[r][h * 4 + 2]; v.w = acc[r][h * 4 + 3];
            *(float4*)&H[(size_t)i * OUTW + j0 + h * 64 + colg * 4] = v;
        }
    }
}

// ---------- conv2 aggregation (gather, no atomics): agg2 = D^-1/2 A D^-1/2 h2m + self + b2 ----------
__global__ __launch_bounds__(256) void k_gather2(const float* __restrict__ h2m,
                                                 const float* __restrict__ dinv,
                                                 const float* __restrict__ b2,
                                                 const int* __restrict__ rowptr,
                                                 const int* __restrict__ ecol,
                                                 float* __restrict__ agg2) {
    int tid = threadIdx.x;
    int d = blockIdx.x * 8 + (tid >> 5);
    int c = (tid & 31) * 4;
    float di = dinv[d];
    const float4 b = *(const float4*)&b2[c];
    const float4 h = *(const float4*)&h2m[(size_t)d * 128 + c];
    float d2 = di * di;
    float4 acc;
    acc.x = h.x * d2 + b.x; acc.y = h.y * d2 + b.y;
    acc.z = h.z * d2 + b.z; acc.w = h.w * d2 + b.w;
    int e0 = rowptr[d], e1 = rowptr[d + 1];
    for (int e = e0; e < e1; ++e) {
        int s = ecol[e];
        float w = di * dinv[s];
        const float4 v = *(const float4*)&h2m[(size_t)s * 128 + c];
        acc.x += v.x * w; acc.y += v.y * w; acc.z += v.z * w; acc.w += v.w * w;
    }
    *(float4*)&agg2[(size_t)d * 128 + c] = acc;
}

// ---------- fused conv3-aggregation + mean-pool + fc1 + fc2, one block per graph ----------
__global__ __launch_bounds__(256) void k_pool_head(const float* __restrict__ h3m,
                                                   const float* __restrict__ dinv,
                                                   const int* __restrict__ rowptr,
                                                   const int* __restrict__ ecol,
                                                   const int* __restrict__ batch,
                                                   const float* __restrict__ b3,
                                                   const float* __restrict__ fc1W,
                                                   const float* __restrict__ fc1b,
                                                   const float* __restrict__ fc2W,
                                                   const float* __restrict__ fc2b,
                                                   float* __restrict__ out) {
    int g = blockIdx.x, tid = threadIdx.x;
    // batch is sorted: binary search node range [lo, hi)
    int l = 0, r = NN;
    while (l < r) { int m = (l + r) >> 1; if (batch[m] < g) l = m + 1; else r = m; }
    int lo = l;
    r = NN;
    while (l < r) { int m = (l + r) >> 1; if (batch[m] < g + 1) l = m + 1; else r = m; }
    int hi = l;
    int cnt = hi - lo;

    int tx = tid & 63, ty = tid >> 6;
    int c = tx * 4;
    float4 acc = {0.f, 0.f, 0.f, 0.f};
    for (int i = lo + ty; i < hi; i += 4) {
        float di = dinv[i], d2 = di * di;
        const float4 hv = *(const float4*)&h3m[(size_t)i * 256 + c];
        acc.x += hv.x * d2; acc.y += hv.y * d2; acc.z += hv.z * d2; acc.w += hv.w * d2;
        int e0 = rowptr[i], e1 = rowptr[i + 1];
        for (int e = e0; e < e1; ++e) {
            int s = ecol[e];
            float w = di * dinv[s];
            const float4 v = *(const float4*)&h3m[(size_t)s * 256 + c];
            acc.x += v.x * w; acc.y += v.y * w; acc.z += v.z * w; acc.w += v.w * w;
        }
    }
    __shared__ float red[4][256];
    __shared__ float mean[256];
    __shared__ float g1[128];
    *(float4*)&red[ty][c] = acc;
    __syncthreads();
    if (tid < 64) {
        int cc = tid * 4;
        const float4 s0 = *(const float4*)&red[0][cc];
        const float4 s1 = *(const float4*)&red[1][cc];
        const float4 s2 = *(const float4*)&red[2][cc];
        const float4 s3 = *(const float4*)&red[3][cc];
        const float4 bv = *(const float4*)&b3[cc];
        float inv = (cnt > 0) ? 1.0f / (float)cnt : 0.0f;
        float4 m;
        m.x = (cnt > 0) ? (s0.x + s1.x + s2.x + s3.x) * inv + bv.x : 0.0f;
        m.y = (cnt > 0) ? (s0.y + s1.y + s2.y + s3.y) * inv + bv.y : 0.0f;
        m.z = (cnt > 0) ? (s0.z + s1.z + s2.z + s3.z) * inv + bv.z : 0.0f;
        m.w = (cnt > 0) ? (s0.w + s1.w + s2.w + s3.w) * inv + bv.w : 0.0f;
        *(float4*)&mean[cc] = m;
    }
    __syncthreads();
    if (tid < 128) {
        float a = fc1b[tid];
        for (int j = 0; j < 256; ++j) a += mean[j] * fc1W[j * 128 + tid];
        g1[tid] = fmaxf(a, 0.0f);
    }
    __syncthreads();
    if (tid < 12) {
        float o = fc2b[tid];
        for (int k = 0; k < 128; ++k) o += g1[k] * fc2W[k * 12 + tid];
        out[g * 12 + tid] = o;
    }
}

extern "C" void kernel_launch(void* const* d_in, const int* in_sizes, int n_in,
                              void* d_out, int out_size, void* d_ws, size_t ws_size,
                              hipStream_t stream) {
    const float* x     = (const float*)d_in[0];
    const int*   ei    = (const int*)d_in[1];
    const int*   batch = (const int*)d_in[2];
    const float* W1    = (const float*)d_in[3];
    const float* b1    = (const float*)d_in[4];
    const float* W2    = (const float*)d_in[5];
    const float* b2    = (const float*)d_in[6];
    const float* W3    = (const float*)d_in[7];
    const float* b3    = (const float*)d_in[8];
    const float* fc1W  = (const float*)d_in[9];
    const float* fc1b  = (const float*)d_in[10];
    const float* fc2W  = (const float*)d_in[11];
    const float* fc2b  = (const float*)d_in[12];
    float* out = (float*)d_out;

    const int* srcp = ei;        // edge_index[0]
    const int* dstp = ei + EE;   // edge_index[1]

    // workspace layout (~205 MB, 16B-aligned big buffers first)
    float* agg2 = (float*)d_ws;                    // N*128
    float* h2m  = agg2 + (size_t)NN * 128;         // N*128 (start of N*256 region)
    float* h3m  = h2m;                             // N*256 (reuses h2m region; h2m dead by then)
    float* dinv = h2m + (size_t)NN * 256;          // N
    float* zbuf = dinv + NN;                       // N
    int* indeg  = (int*)(zbuf + NN);               // N
    int* rowptr = indeg + NN;                      // N+1 (padded to N+4)
    int* cursor = rowptr + NN + 4;                 // N
    int* ecol   = cursor + NN;                     // E

    // CSR build
    hipMemsetAsync(indeg, 0, NN * sizeof(int), stream);
    k_count<<<EE / 256, 256, 0, stream>>>(dstp, indeg);
    k_dinv<<<NN / 256, 256, 0, stream>>>(indeg, dinv);
    k_scan<<<1, 1024, 0, stream>>>(indeg, rowptr);
    hipMemcpyAsync(cursor, rowptr, NN * sizeof(int), hipMemcpyDeviceToDevice, stream);
    k_fill_edges<<<EE / 256, 256, 0, stream>>>(srcp, dstp, cursor, ecol);

    // conv1 collapsed to per-node scalar z
    k_z<<<NN / 256, 256, 0, stream>>>(x, dinv, rowptr, ecol, zbuf);

    // conv2: h2m = relu(z⊗W1+b1) @ W2  (A-tile generated in-kernel)
    k_mm<64, 128, true><<<dim3(NN / 64, 1), 256, 0, stream>>>(
        nullptr, zbuf, W1, b1, W2, h2m);
    k_gather2<<<NN / 8, 256, 0, stream>>>(h2m, dinv, b2, rowptr, ecol, agg2);

    // conv3: h3m = relu(agg2) @ W3
    k_mm<128, 256, false><<<dim3(NN / 64, 2), 256, 0, stream>>>(
        agg2, nullptr, nullptr, nullptr, W3, h3m);

    // fused conv3-aggregation + pooling + head
    k_pool_head<<<GG, 256, 0, stream>>>(h3m, dinv, rowptr, ecol, batch, b3,
                                        fc1W, fc1b, fc2W, fc2b, out);
}

// Round 4
// 227.007 us; speedup vs baseline: 4.6636x; 1.5775x over previous
//
#include <hip/hip_runtime.h>

#define NN 131072   // nodes
#define EE 262144   // edges
#define GG 4096     // graphs

// ---------- CSR build ----------
__global__ void k_count(const int* __restrict__ dst, int* __restrict__ indeg) {
    int e = blockIdx.x * 256 + threadIdx.x;
    if (e < EE) atomicAdd(&indeg[dst[e]], 1);
}

__global__ void k_dinv(const int* __restrict__ indeg, float* __restrict__ dinv) {
    int i = blockIdx.x * 256 + threadIdx.x;
    if (i < NN) dinv[i] = rsqrtf((float)indeg[i] + 1.0f);
}

// exclusive scan of indeg[N] -> rowptr[N+1], single block of 1024 threads, 128 elems each
__global__ __launch_bounds__(1024) void k_scan(const int* __restrict__ indeg,
                                               int* __restrict__ rowptr) {
    __shared__ int ps[1024];
    int tid = threadIdx.x;
    int base = tid * 128;
    int s = 0;
    for (int j = 0; j < 128; ++j) s += indeg[base + j];
    ps[tid] = s;
    __syncthreads();
    for (int off = 1; off < 1024; off <<= 1) {
        int v = (tid >= off) ? ps[tid - off] : 0;
        __syncthreads();
        ps[tid] += v;
        __syncthreads();
    }
    int run = (tid > 0) ? ps[tid - 1] : 0;
    for (int j = 0; j < 128; ++j) {
        rowptr[base + j] = run;
        run += indeg[base + j];
    }
    if (tid == 1023) rowptr[NN] = run;
}

__global__ void k_fill_edges(const int* __restrict__ src, const int* __restrict__ dst,
                             int* __restrict__ cursor, int* __restrict__ ecol) {
    int e = blockIdx.x * 256 + threadIdx.x;
    if (e < EE) {
        int d = dst[e];
        int slot = atomicAdd(&cursor[d], 1);
        ecol[slot] = src[e];
    }
}

// ---------- conv1 scalar: z[i] = dinv_i * (sum_in(x_s*dinv_s) + x_i*dinv_i) ----------
__global__ void k_z(const float* __restrict__ x, const float* __restrict__ dinv,
                    const int* __restrict__ rowptr, const int* __restrict__ ecol,
                    float* __restrict__ z) {
    int i = blockIdx.x * 256 + threadIdx.x;
    if (i < NN) {
        float s = 0.0f;
        int e0 = rowptr[i], e1 = rowptr[i + 1];
        for (int e = e0; e < e1; ++e) {
            int sn = ecol[e];
            s += x[sn] * dinv[sn];
        }
        float di = dinv[i];
        z[i] = di * (s + x[i] * di);
    }
}

// ---------- u = Â relu(z⊗W1+b1)  (conv2 aggregation moved before W2 matmul) ----------
// 16 nodes per block, 16 lanes (float4) per node over the 64-dim.
__global__ __launch_bounds__(256) void k_u(const float* __restrict__ z,
                                           const float* __restrict__ dinv,
                                           const int* __restrict__ rowptr,
                                           const int* __restrict__ ecol,
                                           const float* __restrict__ W1,
                                           const float* __restrict__ b1,
                                           float* __restrict__ u) {
    int tid = threadIdx.x;
    int i = blockIdx.x * 16 + (tid >> 4);
    int lane = tid & 15;
    const float4 w1 = *(const float4*)&W1[lane * 4];
    const float4 bb = *(const float4*)&b1[lane * 4];
    float di = dinv[i];
    float zi = z[i];
    float w0 = di * di;
    float4 acc;
    acc.x = w0 * fmaxf(zi * w1.x + bb.x, 0.f);
    acc.y = w0 * fmaxf(zi * w1.y + bb.y, 0.f);
    acc.z = w0 * fmaxf(zi * w1.z + bb.z, 0.f);
    acc.w = w0 * fmaxf(zi * w1.w + bb.w, 0.f);
    int e0 = rowptr[i], e1 = rowptr[i + 1];
    for (int e = e0; e < e1; ++e) {
        int s = ecol[e];
        float w = di * dinv[s];
        float zs = z[s];
        acc.x += w * fmaxf(zs * w1.x + bb.x, 0.f);
        acc.y += w * fmaxf(zs * w1.y + bb.y, 0.f);
        acc.z += w * fmaxf(zs * w1.z + bb.z, 0.f);
        acc.w += w * fmaxf(zs * w1.w + bb.w, 0.f);
    }
    *(float4*)&u[(size_t)i * 64 + lane * 4] = acc;
}

// ---------- register-tiled fp32 GEMM: C = [relu]( A @ W + bias[*flag] ) ----------
// BM=64, BN=128, KC=64; 256 threads; 4x8 register tile per thread.
// GUARD: bias is added only for rows with cntf[i] > 0 (empty-graph handling).
template <int K, int OUTW, bool RELU_OUT, bool GUARD>
__global__ __launch_bounds__(256) void k_gemm(const float* __restrict__ A,
                                              const float* __restrict__ W,
                                              const float* __restrict__ bias,
                                              const float* __restrict__ cntf,
                                              float* __restrict__ C) {
    __shared__ float At[64][68];     // [row][k], pad keeps 16B alignment
    __shared__ float Wt[64][128];    // [k][col]

    int tid  = threadIdx.x;
    int colg = tid & 15;    // 16 col groups x 8 cols (4+4 split)
    int rowg = tid >> 4;    // 16 row groups x 4 rows
    int i0 = blockIdx.x * 64;
    int j0 = blockIdx.y * 128;

    float acc[4][8];
#pragma unroll
    for (int r = 0; r < 4; ++r)
#pragma unroll
        for (int c = 0; c < 8; ++c) acc[r][c] = 0.0f;

    for (int k0 = 0; k0 < K; k0 += 64) {
        __syncthreads();
        {
            int k4 = tid & 15, r0 = tid >> 4;
#pragma unroll
            for (int p = 0; p < 4; ++p) {
                int r = r0 + p * 16;
                *(float4*)&At[r][k4 * 4] =
                    *(const float4*)&A[(size_t)(i0 + r) * K + k0 + k4 * 4];
            }
        }
        {
            int c4 = tid & 31, kk0 = tid >> 5;
#pragma unroll
            for (int p = 0; p < 8; ++p) {
                int kk = kk0 + p * 8;
                *(float4*)&Wt[kk][c4 * 4] =
                    *(const float4*)&W[(size_t)(k0 + kk) * OUTW + j0 + c4 * 4];
            }
        }
        __syncthreads();
#pragma unroll 4
        for (int kk = 0; kk < 64; ++kk) {
            float a[4];
#pragma unroll
            for (int r = 0; r < 4; ++r) a[r] = At[rowg * 4 + r][kk];
            const float4 w0 = *(const float4*)&Wt[kk][colg * 4];
            const float4 w1 = *(const float4*)&Wt[kk][64 + colg * 4];
            float w[8] = {w0.x, w0.y, w0.z, w0.w, w1.x, w1.y, w1.z, w1.w};
#pragma unroll
            for (int r = 0; r < 4; ++r)
#pragma unroll
                for (int c = 0; c < 8; ++c) acc[r][c] += a[r] * w[c];
        }
    }

#pragma unroll
    for (int r = 0; r < 4; ++r) {
        int i = i0 + rowg * 4 + r;
        float flag = 1.0f;
        if (GUARD) flag = (cntf[i] > 0.0f) ? 1.0f : 0.0f;
#pragma unroll
        for (int h = 0; h < 2; ++h) {
            int j = j0 + h * 64 + colg * 4;
            const float4 b = *(const float4*)&bias[j];
            float4 v;
            v.x = acc[r][h * 4 + 0] + b.x * flag;
            v.y = acc[r][h * 4 + 1] + b.y * flag;
            v.z = acc[r][h * 4 + 2] + b.z * flag;
            v.w = acc[r][h * 4 + 3] + b.w * flag;
            if (RELU_OUT) {
                v.x = fmaxf(v.x, 0.f); v.y = fmaxf(v.y, 0.f);
                v.z = fmaxf(v.z, 0.f); v.w = fmaxf(v.w, 0.f);
            }
            *(float4*)&C[(size_t)i * OUTW + j] = v;
        }
    }
}

// ---------- Y_g = mean_{i in g} ( Â r )_i  over the 128-dim relu'd agg2 ----------
__global__ __launch_bounds__(256) void k_pool(const float* __restrict__ r,
                                              const float* __restrict__ dinv,
                                              const int* __restrict__ rowptr,
                                              const int* __restrict__ ecol,
                                              const int* __restrict__ batch,
                                              float* __restrict__ Y,
                                              float* __restrict__ cntf) {
    int g = blockIdx.x, tid = threadIdx.x;
    // batch sorted: binary search node range [lo, hi)
    int l = 0, rr = NN;
    while (l < rr) { int m = (l + rr) >> 1; if (batch[m] < g) l = m + 1; else rr = m; }
    int lo = l;
    rr = NN;
    while (l < rr) { int m = (l + rr) >> 1; if (batch[m] < g + 1) l = m + 1; else rr = m; }
    int hi = l;
    int cnt = hi - lo;

    int lane = tid & 31, ty = tid >> 5;
    int c = lane * 4;
    float4 acc = {0.f, 0.f, 0.f, 0.f};
    for (int i = lo + ty; i < hi; i += 8) {
        float di = dinv[i], d2 = di * di;
        const float4 hv = *(const float4*)&r[(size_t)i * 128 + c];
        acc.x += hv.x * d2; acc.y += hv.y * d2; acc.z += hv.z * d2; acc.w += hv.w * d2;
        int e0 = rowptr[i], e1 = rowptr[i + 1];
        for (int e = e0; e < e1; ++e) {
            int s = ecol[e];
            float w = di * dinv[s];
            const float4 v = *(const float4*)&r[(size_t)s * 128 + c];
            acc.x += v.x * w; acc.y += v.y * w; acc.z += v.z * w; acc.w += v.w * w;
        }
    }
    __shared__ float red[8][128];
    *(float4*)&red[ty][c] = acc;
    __syncthreads();
    if (tid < 128) {
        float s = 0.0f;
#pragma unroll
        for (int t = 0; t < 8; ++t) s += red[t][tid];
        float inv = (cnt > 0) ? 1.0f / (float)cnt : 0.0f;
        Y[(size_t)g * 128 + tid] = s * inv;
    }
    if (tid == 0) cntf[g] = (float)cnt;
}

// ---------- out = g1 @ fc2W + fc2b  (G x 128 x 12, trivial) ----------
__global__ void k_fc2(const float* __restrict__ g1, const float* __restrict__ W,
                      const float* __restrict__ b, float* __restrict__ out) {
    int t = blockIdx.x * 256 + threadIdx.x;
    if (t < GG * 12) {
        int row = t / 12, col = t % 12;
        float acc = b[col];
        const float* gr = &g1[(size_t)row * 128];
        for (int k = 0; k < 128; ++k) acc += gr[k] * W[k * 12 + col];
        out[t] = acc;
    }
}

extern "C" void kernel_launch(void* const* d_in, const int* in_sizes, int n_in,
                              void* d_out, int out_size, void* d_ws, size_t ws_size,
                              hipStream_t stream) {
    const float* x     = (const float*)d_in[0];
    const int*   ei    = (const int*)d_in[1];
    const int*   batch = (const int*)d_in[2];
    const float* W1    = (const float*)d_in[3];
    const float* b1    = (const float*)d_in[4];
    const float* W2    = (const float*)d_in[5];
    const float* b2    = (const float*)d_in[6];
    const float* W3    = (const float*)d_in[7];
    const float* b3    = (const float*)d_in[8];
    const float* fc1W  = (const float*)d_in[9];
    const float* fc1b  = (const float*)d_in[10];
    const float* fc2W  = (const float*)d_in[11];
    const float* fc2b  = (const float*)d_in[12];
    float* out = (float*)d_out;

    const int* srcp = ei;        // edge_index[0]
    const int* dstp = ei + EE;   // edge_index[1]

    // workspace layout (~112 MB)
    float* r      = (float*)d_ws;                  // N*128  relu(agg2)
    float* u      = r + (size_t)NN * 128;          // N*64
    float* Y      = u + (size_t)NN * 64;           // G*128
    float* pooled = Y + (size_t)GG * 128;          // G*256
    float* g1buf  = pooled + (size_t)GG * 256;     // G*128
    float* cntf   = g1buf + (size_t)GG * 128;      // G
    float* dinv   = cntf + GG;                     // N
    float* zbuf   = dinv + NN;                     // N
    int* indeg  = (int*)(zbuf + NN);               // N
    int* rowptr = indeg + NN;                      // N+4
    int* cursor = rowptr + NN + 4;                 // N
    int* ecol   = cursor + NN;                     // E

    // CSR build
    hipMemsetAsync(indeg, 0, NN * sizeof(int), stream);
    k_count<<<EE / 256, 256, 0, stream>>>(dstp, indeg);
    k_dinv<<<NN / 256, 256, 0, stream>>>(indeg, dinv);
    k_scan<<<1, 1024, 0, stream>>>(indeg, rowptr);
    hipMemcpyAsync(cursor, rowptr, NN * sizeof(int), hipMemcpyDeviceToDevice, stream);
    k_fill_edges<<<EE / 256, 256, 0, stream>>>(srcp, dstp, cursor, ecol);

    // conv1 collapsed to per-node scalar z, then u = Â relu(z⊗W1+b1)
    k_z<<<NN / 256, 256, 0, stream>>>(x, dinv, rowptr, ecol, zbuf);
    k_u<<<NN / 16, 256, 0, stream>>>(zbuf, dinv, rowptr, ecol, W1, b1, u);

    // r = relu(u @ W2 + b2)   (conv2 matmul + conv3-input relu fused)
    k_gemm<64, 128, true, false><<<dim3(NN / 64, 1), 256, 0, stream>>>(
        u, W2, b2, nullptr, r);

    // Y = per-graph mean of Â r  (conv3 aggregation + pooling, pre-matmul)
    k_pool<<<GG, 256, 0, stream>>>(r, dinv, rowptr, ecol, batch, Y, cntf);

    // pooled = Y @ W3 + b3 (guarded for empty graphs)
    k_gemm<128, 256, false, true><<<dim3(GG / 64, 2), 256, 0, stream>>>(
        Y, W3, b3, cntf, pooled);
    // g1 = relu(pooled @ fc1W + fc1b)
    k_gemm<256, 128, true, false><<<dim3(GG / 64, 1), 256, 0, stream>>>(
        pooled, fc1W, fc1b, nullptr, g1buf);
    // out = g1 @ fc2W + fc2b
    k_fc2<<<(GG * 12 + 255) / 256, 256, 0, stream>>>(g1buf, fc2W, fc2b, out);
}

// Round 5
// 181.949 us; speedup vs baseline: 5.8185x; 1.2476x over previous
//
#include <hip/hip_runtime.h>

#define NN 131072   // nodes
#define EE 262144   // edges
#define GG 4096     // graphs

// ---------- CSR build ----------
__global__ void k_count(const int* __restrict__ dst, int* __restrict__ indeg) {
    int e = blockIdx.x * 256 + threadIdx.x;
    if (e < EE) atomicAdd(&indeg[dst[e]], 1);
}

__global__ void k_dinv(const int* __restrict__ indeg, float* __restrict__ dinv) {
    int i = blockIdx.x * 256 + threadIdx.x;
    if (i < NN) dinv[i] = rsqrtf((float)indeg[i] + 1.0f);
}

// --- hierarchical exclusive scan of indeg[N] -> rowptr[N+1] (and cursor copy) ---
// A: per-block (256 elems) totals
__global__ __launch_bounds__(256) void k_scan_a(const int* __restrict__ indeg,
                                                int* __restrict__ bsum) {
    __shared__ int red[256];
    int tid = threadIdx.x;
    red[tid] = indeg[blockIdx.x * 256 + tid];
    __syncthreads();
#pragma unroll
    for (int off = 128; off > 0; off >>= 1) {
        if (tid < off) red[tid] += red[tid + off];
        __syncthreads();
    }
    if (tid == 0) bsum[blockIdx.x] = red[0];
}

// B: single block, exclusive scan of bsum[512] -> boff[513]
__global__ __launch_bounds__(512) void k_scan_b(const int* __restrict__ bsum,
                                                int* __restrict__ boff) {
    __shared__ int ps[512];
    int tid = threadIdx.x;
    ps[tid] = bsum[tid];
    __syncthreads();
    for (int off = 1; off < 512; off <<= 1) {
        int v = (tid >= off) ? ps[tid - off] : 0;
        __syncthreads();
        ps[tid] += v;
        __syncthreads();
    }
    boff[tid] = (tid > 0) ? ps[tid - 1] : 0;
    if (tid == 511) boff[512] = ps[511];
}

// C: per-block local exclusive scan + block offset -> rowptr & cursor
__global__ __launch_bounds__(256) void k_scan_c(const int* __restrict__ indeg,
                                                const int* __restrict__ boff,
                                                int* __restrict__ rowptr,
                                                int* __restrict__ cursor) {
    __shared__ int ps[256];
    int tid = threadIdx.x;
    int gid = blockIdx.x * 256 + tid;
    int v = indeg[gid];
    ps[tid] = v;
    __syncthreads();
    for (int off = 1; off < 256; off <<= 1) {
        int t = (tid >= off) ? ps[tid - off] : 0;
        __syncthreads();
        ps[tid] += t;
        __syncthreads();
    }
    int excl = boff[blockIdx.x] + ps[tid] - v;
    rowptr[gid] = excl;
    cursor[gid] = excl;
    if (gid == NN - 1) rowptr[NN] = boff[512];
}

__global__ void k_fill_edges(const int* __restrict__ src, const int* __restrict__ dst,
                             int* __restrict__ cursor, int* __restrict__ ecol) {
    int e = blockIdx.x * 256 + threadIdx.x;
    if (e < EE) {
        int d = dst[e];
        int slot = atomicAdd(&cursor[d], 1);
        ecol[slot] = src[e];
    }
}

// ---------- conv1 scalar: z[i] = dinv_i * (sum_in(x_s*dinv_s) + x_i*dinv_i) ----------
__global__ void k_z(const float* __restrict__ x, const float* __restrict__ dinv,
                    const int* __restrict__ rowptr, const int* __restrict__ ecol,
                    float* __restrict__ z) {
    int i = blockIdx.x * 256 + threadIdx.x;
    if (i < NN) {
        float s = 0.0f;
        int e0 = rowptr[i], e1 = rowptr[i + 1];
        for (int e = e0; e < e1; ++e) {
            int sn = ecol[e];
            s += x[sn] * dinv[sn];
        }
        float di = dinv[i];
        z[i] = di * (s + x[i] * di);
    }
}

// ---------- u = Â relu(z⊗W1+b1)  (conv2 aggregation moved before W2 matmul) ----------
__global__ __launch_bounds__(256) void k_u(const float* __restrict__ z,
                                           const float* __restrict__ dinv,
                                           const int* __restrict__ rowptr,
                                           const int* __restrict__ ecol,
                                           const float* __restrict__ W1,
                                           const float* __restrict__ b1,
                                           float* __restrict__ u) {
    int tid = threadIdx.x;
    int i = blockIdx.x * 16 + (tid >> 4);
    int lane = tid & 15;
    const float4 w1 = *(const float4*)&W1[lane * 4];
    const float4 bb = *(const float4*)&b1[lane * 4];
    float di = dinv[i];
    float zi = z[i];
    float w0 = di * di;
    float4 acc;
    acc.x = w0 * fmaxf(zi * w1.x + bb.x, 0.f);
    acc.y = w0 * fmaxf(zi * w1.y + bb.y, 0.f);
    acc.z = w0 * fmaxf(zi * w1.z + bb.z, 0.f);
    acc.w = w0 * fmaxf(zi * w1.w + bb.w, 0.f);
    int e0 = rowptr[i], e1 = rowptr[i + 1];
    for (int e = e0; e < e1; ++e) {
        int s = ecol[e];
        float w = di * dinv[s];
        float zs = z[s];
        acc.x += w * fmaxf(zs * w1.x + bb.x, 0.f);
        acc.y += w * fmaxf(zs * w1.y + bb.y, 0.f);
        acc.z += w * fmaxf(zs * w1.z + bb.z, 0.f);
        acc.w += w * fmaxf(zs * w1.w + bb.w, 0.f);
    }
    *(float4*)&u[(size_t)i * 64 + lane * 4] = acc;
}

// ---------- register-tiled fp32 GEMM: C = [relu]( A @ W + bias[*flag] ) ----------
template <int K, int OUTW, bool RELU_OUT, bool GUARD>
__global__ __launch_bounds__(256) void k_gemm(const float* __restrict__ A,
                                              const float* __restrict__ W,
                                              const float* __restrict__ bias,
                                              const float* __restrict__ cntf,
                                              float* __restrict__ C) {
    __shared__ float At[64][68];
    __shared__ float Wt[64][128];

    int tid  = threadIdx.x;
    int colg = tid & 15;
    int rowg = tid >> 4;
    int i0 = blockIdx.x * 64;
    int j0 = blockIdx.y * 128;

    float acc[4][8];
#pragma unroll
    for (int r = 0; r < 4; ++r)
#pragma unroll
        for (int c = 0; c < 8; ++c) acc[r][c] = 0.0f;

    for (int k0 = 0; k0 < K; k0 += 64) {
        __syncthreads();
        {
            int k4 = tid & 15, r0 = tid >> 4;
#pragma unroll
            for (int p = 0; p < 4; ++p) {
                int r = r0 + p * 16;
                *(float4*)&At[r][k4 * 4] =
                    *(const float4*)&A[(size_t)(i0 + r) * K + k0 + k4 * 4];
            }
        }
        {
            int c4 = tid & 31, kk0 = tid >> 5;
#pragma unroll
            for (int p = 0; p < 8; ++p) {
                int kk = kk0 + p * 8;
                *(float4*)&Wt[kk][c4 * 4] =
                    *(const float4*)&W[(size_t)(k0 + kk) * OUTW + j0 + c4 * 4];
            }
        }
        __syncthreads();
#pragma unroll 4
        for (int kk = 0; kk < 64; ++kk) {
            float a[4];
#pragma unroll
            for (int r = 0; r < 4; ++r) a[r] = At[rowg * 4 + r][kk];
            const float4 w0 = *(const float4*)&Wt[kk][colg * 4];
            const float4 w1 = *(const float4*)&Wt[kk][64 + colg * 4];
            float w[8] = {w0.x, w0.y, w0.z, w0.w, w1.x, w1.y, w1.z, w1.w};
#pragma unroll
            for (int r = 0; r < 4; ++r)
#pragma unroll
                for (int c = 0; c < 8; ++c) acc[r][c] += a[r] * w[c];
        }
    }

#pragma unroll
    for (int r = 0; r < 4; ++r) {
        int i = i0 + rowg * 4 + r;
        float flag = 1.0f;
        if (GUARD) flag = (cntf[i] > 0.0f) ? 1.0f : 0.0f;
#pragma unroll
        for (int h = 0; h < 2; ++h) {
            int j = j0 + h * 64 + colg * 4;
            const float4 b = *(const float4*)&bias[j];
            float4 v;
            v.x = acc[r][h * 4 + 0] + b.x * flag;
            v.y = acc[r][h * 4 + 1] + b.y * flag;
            v.z = acc[r][h * 4 + 2] + b.z * flag;
            v.w = acc[r][h * 4 + 3] + b.w * flag;
            if (RELU_OUT) {
                v.x = fmaxf(v.x, 0.f); v.y = fmaxf(v.y, 0.f);
                v.z = fmaxf(v.z, 0.f); v.w = fmaxf(v.w, 0.f);
            }
            *(float4*)&C[(size_t)i * OUTW + j] = v;
        }
    }
}

// ---------- Y_g = mean_{i in g} ( Â r )_i  over the 128-dim relu'd agg2 ----------
__global__ __launch_bounds__(256) void k_pool(const float* __restrict__ r,
                                              const float* __restrict__ dinv,
                                              const int* __restrict__ rowptr,
                                              const int* __restrict__ ecol,
                                              const int* __restrict__ batch,
                                              float* __restrict__ Y,
                                              float* __restrict__ cntf) {
    int g = blockIdx.x, tid = threadIdx.x;
    int l = 0, rr = NN;
    while (l < rr) { int m = (l + rr) >> 1; if (batch[m] < g) l = m + 1; else rr = m; }
    int lo = l;
    rr = NN;
    while (l < rr) { int m = (l + rr) >> 1; if (batch[m] < g + 1) l = m + 1; else rr = m; }
    int hi = l;
    int cnt = hi - lo;

    int lane = tid & 31, ty = tid >> 5;
    int c = lane * 4;
    float4 acc = {0.f, 0.f, 0.f, 0.f};
    for (int i = lo + ty; i < hi; i += 8) {
        float di = dinv[i], d2 = di * di;
        const float4 hv = *(const float4*)&r[(size_t)i * 128 + c];
        acc.x += hv.x * d2; acc.y += hv.y * d2; acc.z += hv.z * d2; acc.w += hv.w * d2;
        int e0 = rowptr[i], e1 = rowptr[i + 1];
        for (int e = e0; e < e1; ++e) {
            int s = ecol[e];
            float w = di * dinv[s];
            const float4 v = *(const float4*)&r[(size_t)s * 128 + c];
            acc.x += v.x * w; acc.y += v.y * w; acc.z += v.z * w; acc.w += v.w * w;
        }
    }
    __shared__ float red[8][128];
    *(float4*)&red[ty][c] = acc;
    __syncthreads();
    if (tid < 128) {
        float s = 0.0f;
#pragma unroll
        for (int t = 0; t < 8; ++t) s += red[t][tid];
        float inv = (cnt > 0) ? 1.0f / (float)cnt : 0.0f;
        Y[(size_t)g * 128 + tid] = s * inv;
    }
    if (tid == 0) cntf[g] = (float)cnt;
}

// ---------- out = g1 @ fc2W + fc2b ----------
__global__ void k_fc2(const float* __restrict__ g1, const float* __restrict__ W,
                      const float* __restrict__ b, float* __restrict__ out) {
    int t = blockIdx.x * 256 + threadIdx.x;
    if (t < GG * 12) {
        int row = t / 12, col = t % 12;
        float acc = b[col];
        const float* gr = &g1[(size_t)row * 128];
        for (int k = 0; k < 128; ++k) acc += gr[k] * W[k * 12 + col];
        out[t] = acc;
    }
}

extern "C" void kernel_launch(void* const* d_in, const int* in_sizes, int n_in,
                              void* d_out, int out_size, void* d_ws, size_t ws_size,
                              hipStream_t stream) {
    const float* x     = (const float*)d_in[0];
    const int*   ei    = (const int*)d_in[1];
    const int*   batch = (const int*)d_in[2];
    const float* W1    = (const float*)d_in[3];
    const float* b1    = (const float*)d_in[4];
    const float* W2    = (const float*)d_in[5];
    const float* b2    = (const float*)d_in[6];
    const float* W3    = (const float*)d_in[7];
    const float* b3    = (const float*)d_in[8];
    const float* fc1W  = (const float*)d_in[9];
    const float* fc1b  = (const float*)d_in[10];
    const float* fc2W  = (const float*)d_in[11];
    const float* fc2b  = (const float*)d_in[12];
    float* out = (float*)d_out;

    const int* srcp = ei;        // edge_index[0]
    const int* dstp = ei + EE;   // edge_index[1]

    // workspace layout (~112 MB)
    float* r      = (float*)d_ws;                  // N*128  relu(agg2)
    float* u      = r + (size_t)NN * 128;          // N*64
    float* Y      = u + (size_t)NN * 64;           // G*128
    float* pooled = Y + (size_t)GG * 128;          // G*256
    float* g1buf  = pooled + (size_t)GG * 256;     // G*128
    float* cntf   = g1buf + (size_t)GG * 128;      // G
    float* dinv   = cntf + GG;                     // N
    float* zbuf   = dinv + NN;                     // N
    int* indeg  = (int*)(zbuf + NN);               // N
    int* rowptr = indeg + NN;                      // N+4
    int* cursor = rowptr + NN + 4;                 // N
    int* ecol   = cursor + NN;                     // E
    int* bsum   = ecol + EE;                       // 512
    int* boff   = bsum + 512;                      // 513

    // CSR build
    hipMemsetAsync(indeg, 0, NN * sizeof(int), stream);
    k_count<<<EE / 256, 256, 0, stream>>>(dstp, indeg);
    k_dinv<<<NN / 256, 256, 0, stream>>>(indeg, dinv);
    k_scan_a<<<NN / 256, 256, 0, stream>>>(indeg, bsum);
    k_scan_b<<<1, 512, 0, stream>>>(bsum, boff);
    k_scan_c<<<NN / 256, 256, 0, stream>>>(indeg, boff, rowptr, cursor);
    k_fill_edges<<<EE / 256, 256, 0, stream>>>(srcp, dstp, cursor, ecol);

    // conv1 collapsed to per-node scalar z, then u = Â relu(z⊗W1+b1)
    k_z<<<NN / 256, 256, 0, stream>>>(x, dinv, rowptr, ecol, zbuf);
    k_u<<<NN / 16, 256, 0, stream>>>(zbuf, dinv, rowptr, ecol, W1, b1, u);

    // r = relu(u @ W2 + b2)
    k_gemm<64, 128, true, false><<<dim3(NN / 64, 1), 256, 0, stream>>>(
        u, W2, b2, nullptr, r);

    // Y = per-graph mean of Â r
    k_pool<<<GG, 256, 0, stream>>>(r, dinv, rowptr, ecol, batch, Y, cntf);

    // pooled = Y @ W3 + b3 (guarded for empty graphs)
    k_gemm<128, 256, false, true><<<dim3(GG / 64, 2), 256, 0, stream>>>(
        Y, W3, b3, cntf, pooled);
    // g1 = relu(pooled @ fc1W + fc1b)
    k_gemm<256, 128, true, false><<<dim3(GG / 64, 1), 256, 0, stream>>>(
        pooled, fc1W, fc1b, nullptr, g1buf);
    // out = g1 @ fc2W + fc2b
    k_fc2<<<(GG * 12 + 255) / 256, 256, 0, stream>>>(g1buf, fc2W, fc2b, out);
}

// Round 6
// 162.633 us; speedup vs baseline: 6.5096x; 1.1188x over previous
//
#include <hip/hip_runtime.h>

#define NN 131072   // nodes
#define EE 262144   // edges
#define GG 4096     // graphs

// ---------- CSR build ----------
__global__ void k_count(const int* __restrict__ dst, int* __restrict__ indeg) {
    int e = blockIdx.x * 256 + threadIdx.x;
    if (e < EE) atomicAdd(&indeg[dst[e]], 1);
}

// A: per-block (256 elems) totals + dinv
__global__ __launch_bounds__(256) void k_scan_a(const int* __restrict__ indeg,
                                                int* __restrict__ bsum,
                                                float* __restrict__ dinv) {
    __shared__ int red[256];
    int tid = threadIdx.x;
    int gid = blockIdx.x * 256 + tid;
    int v = indeg[gid];
    dinv[gid] = rsqrtf((float)v + 1.0f);
    red[tid] = v;
    __syncthreads();
#pragma unroll
    for (int off = 128; off > 0; off >>= 1) {
        if (tid < off) red[tid] += red[tid + off];
        __syncthreads();
    }
    if (tid == 0) bsum[blockIdx.x] = red[0];
}

// B: single block, exclusive scan of bsum[512] -> boff[513]
__global__ __launch_bounds__(512) void k_scan_b(const int* __restrict__ bsum,
                                                int* __restrict__ boff) {
    __shared__ int ps[512];
    int tid = threadIdx.x;
    ps[tid] = bsum[tid];
    __syncthreads();
    for (int off = 1; off < 512; off <<= 1) {
        int v = (tid >= off) ? ps[tid - off] : 0;
        __syncthreads();
        ps[tid] += v;
        __syncthreads();
    }
    boff[tid] = (tid > 0) ? ps[tid - 1] : 0;
    if (tid == 511) boff[512] = ps[511];
}

// C: per-block local exclusive scan + block offset -> rowptr & cursor
__global__ __launch_bounds__(256) void k_scan_c(const int* __restrict__ indeg,
                                                const int* __restrict__ boff,
                                                int* __restrict__ rowptr,
                                                int* __restrict__ cursor) {
    __shared__ int ps[256];
    int tid = threadIdx.x;
    int gid = blockIdx.x * 256 + tid;
    int v = indeg[gid];
    ps[tid] = v;
    __syncthreads();
    for (int off = 1; off < 256; off <<= 1) {
        int t = (tid >= off) ? ps[tid - off] : 0;
        __syncthreads();
        ps[tid] += t;
        __syncthreads();
    }
    int excl = boff[blockIdx.x] + ps[tid] - v;
    rowptr[gid] = excl;
    cursor[gid] = excl;
    if (gid == NN - 1) rowptr[NN] = boff[512];
}

// fill ecol + per-slot coefficient ecoef = dinv[d]*dinv[s]
__global__ void k_fill_edges(const int* __restrict__ src, const int* __restrict__ dst,
                             const float* __restrict__ dinv,
                             int* __restrict__ cursor, int* __restrict__ ecol,
                             float* __restrict__ ecoef) {
    int e = blockIdx.x * 256 + threadIdx.x;
    if (e < EE) {
        int d = dst[e], s = src[e];
        int slot = atomicAdd(&cursor[d], 1);
        ecol[slot] = s;
        ecoef[slot] = dinv[d] * dinv[s];
    }
}

// ---------- conv1 scalar: z[i] = x_i*dinv_i^2 + sum_e ecoef[e]*x[ecol[e]] ----------
__global__ void k_z(const float* __restrict__ x, const float* __restrict__ dinv,
                    const int* __restrict__ rowptr, const int* __restrict__ ecol,
                    const float* __restrict__ ecoef, float* __restrict__ z) {
    int i = blockIdx.x * 256 + threadIdx.x;
    if (i < NN) {
        float di = dinv[i];
        float s = x[i] * di * di;
        int e0 = rowptr[i], e1 = rowptr[i + 1];
        for (int e = e0; e < e1; ++e) s += ecoef[e] * x[ecol[e]];
        z[i] = s;
    }
}

// ---------- fused conv2: r = relu( [Â relu(z⊗W1+b1)] @ W2 + b2 ) ----------
// A-tile (u rows) generated in-prologue from z; single K-chunk (K=64), OUT=128.
__global__ __launch_bounds__(256) void k_gemm2u(const float* __restrict__ z,
                                                const float* __restrict__ dinv,
                                                const int* __restrict__ rowptr,
                                                const int* __restrict__ ecol,
                                                const float* __restrict__ ecoef,
                                                const float* __restrict__ W1,
                                                const float* __restrict__ b1,
                                                const float* __restrict__ W2,
                                                const float* __restrict__ b2,
                                                float* __restrict__ r) {
    __shared__ float At[64][68];
    __shared__ float Wt[64][128];
    __shared__ float w1s[64], b1s[64];

    int tid = threadIdx.x;
    int i0 = blockIdx.x * 64;

    if (tid < 64) { w1s[tid] = W1[tid]; b1s[tid] = b1[tid]; }
    {   // stage W2 [64][128]
        int c4 = tid & 31, kk0 = tid >> 5;
#pragma unroll
        for (int p = 0; p < 8; ++p) {
            int kk = kk0 + p * 8;
            *(float4*)&Wt[kk][c4 * 4] = *(const float4*)&W2[(size_t)kk * 128 + c4 * 4];
        }
    }
    __syncthreads();

    {   // generate u rows: 4 threads per node, 16 k's each
        int n = tid >> 2;
        int k0 = (tid & 3) * 16;
        int i = i0 + n;
        float zi = z[i], di = dinv[i];
        float d2 = di * di;
        float uacc[16];
#pragma unroll
        for (int j = 0; j < 16; ++j)
            uacc[j] = d2 * fmaxf(zi * w1s[k0 + j] + b1s[k0 + j], 0.f);
        int e0 = rowptr[i], e1 = rowptr[i + 1];
        for (int e = e0; e < e1; ++e) {
            float w = ecoef[e];
            float zs = z[ecol[e]];
#pragma unroll
            for (int j = 0; j < 16; ++j)
                uacc[j] += w * fmaxf(zs * w1s[k0 + j] + b1s[k0 + j], 0.f);
        }
#pragma unroll
        for (int j = 0; j < 16; ++j) At[n][k0 + j] = uacc[j];
    }
    __syncthreads();

    int colg = tid & 15;
    int rowg = tid >> 4;
    float acc[4][8];
#pragma unroll
    for (int rr = 0; rr < 4; ++rr)
#pragma unroll
        for (int c = 0; c < 8; ++c) acc[rr][c] = 0.0f;

#pragma unroll 4
    for (int kk = 0; kk < 64; ++kk) {
        float a[4];
#pragma unroll
        for (int rr = 0; rr < 4; ++rr) a[rr] = At[rowg * 4 + rr][kk];
        const float4 w0 = *(const float4*)&Wt[kk][colg * 4];
        const float4 w1 = *(const float4*)&Wt[kk][64 + colg * 4];
        float w[8] = {w0.x, w0.y, w0.z, w0.w, w1.x, w1.y, w1.z, w1.w};
#pragma unroll
        for (int rr = 0; rr < 4; ++rr)
#pragma unroll
            for (int c = 0; c < 8; ++c) acc[rr][c] += a[rr] * w[c];
    }

#pragma unroll
    for (int rr = 0; rr < 4; ++rr) {
        int i = i0 + rowg * 4 + rr;
#pragma unroll
        for (int h = 0; h < 2; ++h) {
            int j = h * 64 + colg * 4;
            const float4 b = *(const float4*)&b2[j];
            float4 v;
            v.x = fmaxf(acc[rr][h * 4 + 0] + b.x, 0.f);
            v.y = fmaxf(acc[rr][h * 4 + 1] + b.y, 0.f);
            v.z = fmaxf(acc[rr][h * 4 + 2] + b.z, 0.f);
            v.w = fmaxf(acc[rr][h * 4 + 3] + b.w, 0.f);
            *(float4*)&r[(size_t)i * 128 + j] = v;
        }
    }
}

// ---------- generic register-tiled GEMM (head): C = [relu](A @ W + bias[*flag]) ----------
template <int K, int OUTW, bool RELU_OUT, bool GUARD>
__global__ __launch_bounds__(256) void k_gemm(const float* __restrict__ A,
                                              const float* __restrict__ W,
                                              const float* __restrict__ bias,
                                              const float* __restrict__ cntf,
                                              float* __restrict__ C) {
    __shared__ float At[64][68];
    __shared__ float Wt[64][128];

    int tid  = threadIdx.x;
    int colg = tid & 15;
    int rowg = tid >> 4;
    int i0 = blockIdx.x * 64;
    int j0 = blockIdx.y * 128;

    float acc[4][8];
#pragma unroll
    for (int r = 0; r < 4; ++r)
#pragma unroll
        for (int c = 0; c < 8; ++c) acc[r][c] = 0.0f;

    for (int k0 = 0; k0 < K; k0 += 64) {
        __syncthreads();
        {
            int k4 = tid & 15, r0 = tid >> 4;
#pragma unroll
            for (int p = 0; p < 4; ++p) {
                int r = r0 + p * 16;
                *(float4*)&At[r][k4 * 4] =
                    *(const float4*)&A[(size_t)(i0 + r) * K + k0 + k4 * 4];
            }
        }
        {
            int c4 = tid & 31, kk0 = tid >> 5;
#pragma unroll
            for (int p = 0; p < 8; ++p) {
                int kk = kk0 + p * 8;
                *(float4*)&Wt[kk][c4 * 4] =
                    *(const float4*)&W[(size_t)(k0 + kk) * OUTW + j0 + c4 * 4];
            }
        }
        __syncthreads();
#pragma unroll 4
        for (int kk = 0; kk < 64; ++kk) {
            float a[4];
#pragma unroll
            for (int r = 0; r < 4; ++r) a[r] = At[rowg * 4 + r][kk];
            const float4 w0 = *(const float4*)&Wt[kk][colg * 4];
            const float4 w1 = *(const float4*)&Wt[kk][64 + colg * 4];
            float w[8] = {w0.x, w0.y, w0.z, w0.w, w1.x, w1.y, w1.z, w1.w};
#pragma unroll
            for (int r = 0; r < 4; ++r)
#pragma unroll
                for (int c = 0; c < 8; ++c) acc[r][c] += a[r] * w[c];
        }
    }

#pragma unroll
    for (int r = 0; r < 4; ++r) {
        int i = i0 + rowg * 4 + r;
        float flag = 1.0f;
        if (GUARD) flag = (cntf[i] > 0.0f) ? 1.0f : 0.0f;
#pragma unroll
        for (int h = 0; h < 2; ++h) {
            int j = j0 + h * 64 + colg * 4;
            const float4 b = *(const float4*)&bias[j];
            float4 v;
            v.x = acc[r][h * 4 + 0] + b.x * flag;
            v.y = acc[r][h * 4 + 1] + b.y * flag;
            v.z = acc[r][h * 4 + 2] + b.z * flag;
            v.w = acc[r][h * 4 + 3] + b.w * flag;
            if (RELU_OUT) {
                v.x = fmaxf(v.x, 0.f); v.y = fmaxf(v.y, 0.f);
                v.z = fmaxf(v.z, 0.f); v.w = fmaxf(v.w, 0.f);
            }
            *(float4*)&C[(size_t)i * OUTW + j] = v;
        }
    }
}

// ---------- Y_g = mean_{i in g}(Â r)_i, flat node loop + flat contiguous edge loop ----------
__global__ __launch_bounds__(256) void k_pool(const float* __restrict__ r,
                                              const float* __restrict__ dinv,
                                              const int* __restrict__ rowptr,
                                              const int* __restrict__ ecol,
                                              const float* __restrict__ ecoef,
                                              const int* __restrict__ batch,
                                              float* __restrict__ Y,
                                              float* __restrict__ cntf) {
    int g = blockIdx.x, tid = threadIdx.x;
    // batch sorted: binary search node range [lo, hi)
    int l = 0, rr = NN;
    while (l < rr) { int m = (l + rr) >> 1; if (batch[m] < g) l = m + 1; else rr = m; }
    int lo = l;
    rr = NN;
    while (l < rr) { int m = (l + rr) >> 1; if (batch[m] < g + 1) l = m + 1; else rr = m; }
    int hi = l;
    int cnt = hi - lo;

    int lane = tid & 31, ty = tid >> 5;
    int c = lane * 4;
    float4 acc = {0.f, 0.f, 0.f, 0.f};
    // self terms
    for (int i = lo + ty; i < hi; i += 8) {
        float di = dinv[i], d2 = di * di;
        const float4 v = *(const float4*)&r[(size_t)i * 128 + c];
        acc.x += v.x * d2; acc.y += v.y * d2; acc.z += v.z * d2; acc.w += v.w * d2;
    }
    // edge terms: CSR slots for dst in [lo,hi) are contiguous
    int e0 = rowptr[lo], e1 = rowptr[hi];
    for (int e = e0 + ty; e < e1; e += 8) {
        int s = ecol[e];
        float w = ecoef[e];
        const float4 v = *(const float4*)&r[(size_t)s * 128 + c];
        acc.x += v.x * w; acc.y += v.y * w; acc.z += v.z * w; acc.w += v.w * w;
    }
    __shared__ float red[8][128];
    *(float4*)&red[ty][c] = acc;
    __syncthreads();
    if (tid < 128) {
        float s = 0.0f;
#pragma unroll
        for (int t = 0; t < 8; ++t) s += red[t][tid];
        float inv = (cnt > 0) ? 1.0f / (float)cnt : 0.0f;
        Y[(size_t)g * 128 + tid] = s * inv;
    }
    if (tid == 0) cntf[g] = (float)cnt;
}

// ---------- out = g1 @ fc2W + fc2b ----------
__global__ void k_fc2(const float* __restrict__ g1, const float* __restrict__ W,
                      const float* __restrict__ b, float* __restrict__ out) {
    int t = blockIdx.x * 256 + threadIdx.x;
    if (t < GG * 12) {
        int row = t / 12, col = t % 12;
        float acc = b[col];
        const float* gr = &g1[(size_t)row * 128];
        for (int k = 0; k < 128; ++k) acc += gr[k] * W[k * 12 + col];
        out[t] = acc;
    }
}

extern "C" void kernel_launch(void* const* d_in, const int* in_sizes, int n_in,
                              void* d_out, int out_size, void* d_ws, size_t ws_size,
                              hipStream_t stream) {
    const float* x     = (const float*)d_in[0];
    const int*   ei    = (const int*)d_in[1];
    const int*   batch = (const int*)d_in[2];
    const float* W1    = (const float*)d_in[3];
    const float* b1    = (const float*)d_in[4];
    const float* W2    = (const float*)d_in[5];
    const float* b2    = (const float*)d_in[6];
    const float* W3    = (const float*)d_in[7];
    const float* b3    = (const float*)d_in[8];
    const float* fc1W  = (const float*)d_in[9];
    const float* fc1b  = (const float*)d_in[10];
    const float* fc2W  = (const float*)d_in[11];
    const float* fc2b  = (const float*)d_in[12];
    float* out = (float*)d_out;

    const int* srcp = ei;        // edge_index[0]
    const int* dstp = ei + EE;   // edge_index[1]

    // workspace layout (~75 MB)
    float* r      = (float*)d_ws;                  // N*128
    float* Y      = r + (size_t)NN * 128;          // G*128
    float* pooled = Y + (size_t)GG * 128;          // G*256
    float* g1buf  = pooled + (size_t)GG * 256;     // G*128
    float* cntf   = g1buf + (size_t)GG * 128;      // G
    float* dinv   = cntf + GG;                     // N
    float* zbuf   = dinv + NN;                     // N
    float* ecoef  = zbuf + NN;                     // E
    int* indeg  = (int*)(ecoef + EE);              // N
    int* rowptr = indeg + NN;                      // N+4
    int* cursor = rowptr + NN + 4;                 // N
    int* ecol   = cursor + NN;                     // E
    int* bsum   = ecol + EE;                       // 512
    int* boff   = bsum + 512;                      // 513

    // CSR build
    hipMemsetAsync(indeg, 0, NN * sizeof(int), stream);
    k_count<<<EE / 256, 256, 0, stream>>>(dstp, indeg);
    k_scan_a<<<NN / 256, 256, 0, stream>>>(indeg, bsum, dinv);
    k_scan_b<<<1, 512, 0, stream>>>(bsum, boff);
    k_scan_c<<<NN / 256, 256, 0, stream>>>(indeg, boff, rowptr, cursor);
    k_fill_edges<<<EE / 256, 256, 0, stream>>>(srcp, dstp, dinv, cursor, ecol, ecoef);

    // conv1 scalar
    k_z<<<NN / 256, 256, 0, stream>>>(x, dinv, rowptr, ecol, ecoef, zbuf);

    // conv2 fused: r = relu([Â relu(z⊗W1+b1)] @ W2 + b2)
    k_gemm2u<<<NN / 64, 256, 0, stream>>>(zbuf, dinv, rowptr, ecol, ecoef,
                                          W1, b1, W2, b2, r);

    // conv3 aggregation + mean pool
    k_pool<<<GG, 256, 0, stream>>>(r, dinv, rowptr, ecol, ecoef, batch, Y, cntf);

    // head
    k_gemm<128, 256, false, true><<<dim3(GG / 64, 2), 256, 0, stream>>>(
        Y, W3, b3, cntf, pooled);
    k_gemm<256, 128, true, false><<<dim3(GG / 64, 1), 256, 0, stream>>>(
        pooled, fc1W, fc1b, nullptr, g1buf);
    k_fc2<<<(GG * 12 + 255) / 256, 256, 0, stream>>>(g1buf, fc2W, fc2b, out);
}

// Round 7
// 158.134 us; speedup vs baseline: 6.6948x; 1.0285x over previous
//
#include <hip/hip_runtime.h>

#define NN 131072   // nodes
#define EE 262144   // edges
#define GG 4096     // graphs

// ---------- CSR build ----------
__global__ void k_count(const int* __restrict__ dst, int* __restrict__ indeg) {
    int e = blockIdx.x * 256 + threadIdx.x;
    if (e < EE) atomicAdd(&indeg[dst[e]], 1);
}

// A: per-block (256 elems) totals + dinv
__global__ __launch_bounds__(256) void k_scan_a(const int* __restrict__ indeg,
                                                int* __restrict__ bsum,
                                                float* __restrict__ dinv) {
    __shared__ int red[256];
    int tid = threadIdx.x;
    int gid = blockIdx.x * 256 + tid;
    int v = indeg[gid];
    dinv[gid] = rsqrtf((float)v + 1.0f);
    red[tid] = v;
    __syncthreads();
#pragma unroll
    for (int off = 128; off > 0; off >>= 1) {
        if (tid < off) red[tid] += red[tid + off];
        __syncthreads();
    }
    if (tid == 0) bsum[blockIdx.x] = red[0];
}

// B: single block, exclusive scan of bsum[512] -> boff[513]
__global__ __launch_bounds__(512) void k_scan_b(const int* __restrict__ bsum,
                                                int* __restrict__ boff) {
    __shared__ int ps[512];
    int tid = threadIdx.x;
    ps[tid] = bsum[tid];
    __syncthreads();
    for (int off = 1; off < 512; off <<= 1) {
        int v = (tid >= off) ? ps[tid - off] : 0;
        __syncthreads();
        ps[tid] += v;
        __syncthreads();
    }
    boff[tid] = (tid > 0) ? ps[tid - 1] : 0;
    if (tid == 511) boff[512] = ps[511];
}

// C: per-block local exclusive scan + block offset -> rowptr & cursor
__global__ __launch_bounds__(256) void k_scan_c(const int* __restrict__ indeg,
                                                const int* __restrict__ boff,
                                                int* __restrict__ rowptr,
                                                int* __restrict__ cursor) {
    __shared__ int ps[256];
    int tid = threadIdx.x;
    int gid = blockIdx.x * 256 + tid;
    int v = indeg[gid];
    ps[tid] = v;
    __syncthreads();
    for (int off = 1; off < 256; off <<= 1) {
        int t = (tid >= off) ? ps[tid - off] : 0;
        __syncthreads();
        ps[tid] += t;
        __syncthreads();
    }
    int excl = boff[blockIdx.x] + ps[tid] - v;
    rowptr[gid] = excl;
    cursor[gid] = excl;
    if (gid == NN - 1) rowptr[NN] = boff[512];
}

// fill ecol + per-slot coefficient ecoef = dinv[d]*dinv[s]
__global__ void k_fill_edges(const int* __restrict__ src, const int* __restrict__ dst,
                             const float* __restrict__ dinv,
                             int* __restrict__ cursor, int* __restrict__ ecol,
                             float* __restrict__ ecoef) {
    int e = blockIdx.x * 256 + threadIdx.x;
    if (e < EE) {
        int d = dst[e], s = src[e];
        int slot = atomicAdd(&cursor[d], 1);
        ecol[slot] = s;
        ecoef[slot] = dinv[d] * dinv[s];
    }
}

// ---------- conv1 scalar: z[i] = x_i*dinv_i^2 + sum_e ecoef[e]*x[ecol[e]] ----------
__global__ void k_z(const float* __restrict__ x, const float* __restrict__ dinv,
                    const int* __restrict__ rowptr, const int* __restrict__ ecol,
                    const float* __restrict__ ecoef, float* __restrict__ z) {
    int i = blockIdx.x * 256 + threadIdx.x;
    if (i < NN) {
        float di = dinv[i];
        float s = x[i] * di * di;
        int e0 = rowptr[i], e1 = rowptr[i + 1];
        for (int e = e0; e < e1; ++e) s += ecoef[e] * x[ecol[e]];
        z[i] = s;
    }
}

// ---------- fused conv2: r = relu( [Â relu(z⊗W1+b1)] @ W2 + b2 ) ----------
__global__ __launch_bounds__(256) void k_gemm2u(const float* __restrict__ z,
                                                const float* __restrict__ dinv,
                                                const int* __restrict__ rowptr,
                                                const int* __restrict__ ecol,
                                                const float* __restrict__ ecoef,
                                                const float* __restrict__ W1,
                                                const float* __restrict__ b1,
                                                const float* __restrict__ W2,
                                                const float* __restrict__ b2,
                                                float* __restrict__ r) {
    __shared__ float At[64][68];
    __shared__ float Wt[64][128];
    __shared__ float w1s[64], b1s[64];

    int tid = threadIdx.x;
    int i0 = blockIdx.x * 64;

    if (tid < 64) { w1s[tid] = W1[tid]; b1s[tid] = b1[tid]; }
    {   // stage W2 [64][128]
        int c4 = tid & 31, kk0 = tid >> 5;
#pragma unroll
        for (int p = 0; p < 8; ++p) {
            int kk = kk0 + p * 8;
            *(float4*)&Wt[kk][c4 * 4] = *(const float4*)&W2[(size_t)kk * 128 + c4 * 4];
        }
    }
    __syncthreads();

    {   // generate u rows: 4 threads per node, 16 k's each
        int n = tid >> 2;
        int k0 = (tid & 3) * 16;
        int i = i0 + n;
        float zi = z[i], di = dinv[i];
        float d2 = di * di;
        float uacc[16];
#pragma unroll
        for (int j = 0; j < 16; ++j)
            uacc[j] = d2 * fmaxf(zi * w1s[k0 + j] + b1s[k0 + j], 0.f);
        int e0 = rowptr[i], e1 = rowptr[i + 1];
        for (int e = e0; e < e1; ++e) {
            float w = ecoef[e];
            float zs = z[ecol[e]];
#pragma unroll
            for (int j = 0; j < 16; ++j)
                uacc[j] += w * fmaxf(zs * w1s[k0 + j] + b1s[k0 + j], 0.f);
        }
#pragma unroll
        for (int j = 0; j < 16; ++j) At[n][k0 + j] = uacc[j];
    }
    __syncthreads();

    int colg = tid & 15;
    int rowg = tid >> 4;
    float acc[4][8];
#pragma unroll
    for (int rr = 0; rr < 4; ++rr)
#pragma unroll
        for (int c = 0; c < 8; ++c) acc[rr][c] = 0.0f;

#pragma unroll 4
    for (int kk = 0; kk < 64; ++kk) {
        float a[4];
#pragma unroll
        for (int rr = 0; rr < 4; ++rr) a[rr] = At[rowg * 4 + rr][kk];
        const float4 w0 = *(const float4*)&Wt[kk][colg * 4];
        const float4 w1 = *(const float4*)&Wt[kk][64 + colg * 4];
        float w[8] = {w0.x, w0.y, w0.z, w0.w, w1.x, w1.y, w1.z, w1.w};
#pragma unroll
        for (int rr = 0; rr < 4; ++rr)
#pragma unroll
            for (int c = 0; c < 8; ++c) acc[rr][c] += a[rr] * w[c];
    }

#pragma unroll
    for (int rr = 0; rr < 4; ++rr) {
        int i = i0 + rowg * 4 + rr;
#pragma unroll
        for (int h = 0; h < 2; ++h) {
            int j = h * 64 + colg * 4;
            const float4 b = *(const float4*)&b2[j];
            float4 v;
            v.x = fmaxf(acc[rr][h * 4 + 0] + b.x, 0.f);
            v.y = fmaxf(acc[rr][h * 4 + 1] + b.y, 0.f);
            v.z = fmaxf(acc[rr][h * 4 + 2] + b.z, 0.f);
            v.w = fmaxf(acc[rr][h * 4 + 3] + b.w, 0.f);
            *(float4*)&r[(size_t)i * 128 + j] = v;
        }
    }
}

// ---------- generic register-tiled GEMM: C = [relu](A @ W + bias[*flag]) ----------
template <int K, int OUTW, bool RELU_OUT, bool GUARD>
__global__ __launch_bounds__(256) void k_gemm(const float* __restrict__ A,
                                              const float* __restrict__ W,
                                              const float* __restrict__ bias,
                                              const float* __restrict__ cntf,
                                              float* __restrict__ C) {
    __shared__ float At[64][68];
    __shared__ float Wt[64][128];

    int tid  = threadIdx.x;
    int colg = tid & 15;
    int rowg = tid >> 4;
    int i0 = blockIdx.x * 64;
    int j0 = blockIdx.y * 128;

    float acc[4][8];
#pragma unroll
    for (int r = 0; r < 4; ++r)
#pragma unroll
        for (int c = 0; c < 8; ++c) acc[r][c] = 0.0f;

    for (int k0 = 0; k0 < K; k0 += 64) {
        __syncthreads();
        {
            int k4 = tid & 15, r0 = tid >> 4;
#pragma unroll
            for (int p = 0; p < 4; ++p) {
                int r = r0 + p * 16;
                *(float4*)&At[r][k4 * 4] =
                    *(const float4*)&A[(size_t)(i0 + r) * K + k0 + k4 * 4];
            }
        }
        {
            int c4 = tid & 31, kk0 = tid >> 5;
#pragma unroll
            for (int p = 0; p < 8; ++p) {
                int kk = kk0 + p * 8;
                *(float4*)&Wt[kk][c4 * 4] =
                    *(const float4*)&W[(size_t)(k0 + kk) * OUTW + j0 + c4 * 4];
            }
        }
        __syncthreads();
#pragma unroll 4
        for (int kk = 0; kk < 64; ++kk) {
            float a[4];
#pragma unroll
            for (int r = 0; r < 4; ++r) a[r] = At[rowg * 4 + r][kk];
            const float4 w0 = *(const float4*)&Wt[kk][colg * 4];
            const float4 w1 = *(const float4*)&Wt[kk][64 + colg * 4];
            float w[8] = {w0.x, w0.y, w0.z, w0.w, w1.x, w1.y, w1.z, w1.w};
#pragma unroll
            for (int r = 0; r < 4; ++r)
#pragma unroll
                for (int c = 0; c < 8; ++c) acc[r][c] += a[r] * w[c];
        }
    }

#pragma unroll
    for (int r = 0; r < 4; ++r) {
        int i = i0 + rowg * 4 + r;
        float flag = 1.0f;
        if (GUARD) flag = (cntf[i] > 0.0f) ? 1.0f : 0.0f;
#pragma unroll
        for (int h = 0; h < 2; ++h) {
            int j = j0 + h * 64 + colg * 4;
            const float4 b = *(const float4*)&bias[j];
            float4 v;
            v.x = acc[r][h * 4 + 0] + b.x * flag;
            v.y = acc[r][h * 4 + 1] + b.y * flag;
            v.z = acc[r][h * 4 + 2] + b.z * flag;
            v.w = acc[r][h * 4 + 3] + b.w * flag;
            if (RELU_OUT) {
                v.x = fmaxf(v.x, 0.f); v.y = fmaxf(v.y, 0.f);
                v.z = fmaxf(v.z, 0.f); v.w = fmaxf(v.w, 0.f);
            }
            *(float4*)&C[(size_t)i * OUTW + j] = v;
        }
    }
}

// ---------- fused head tail: g1 = relu(pooled @ fc1W + fc1b); out = g1 @ fc2W + fc2b ----------
__global__ __launch_bounds__(256) void k_fc12(const float* __restrict__ A,     // pooled G x 256
                                              const float* __restrict__ W,     // fc1W 256 x 128
                                              const float* __restrict__ bias,  // fc1b
                                              const float* __restrict__ fc2W,  // 128 x 12
                                              const float* __restrict__ fc2b,  // 12
                                              float* __restrict__ out) {
    __shared__ float At[64][68];
    __shared__ float Wt[64][128];    // reused as g1 tile after main loop

    int tid  = threadIdx.x;
    int colg = tid & 15;
    int rowg = tid >> 4;
    int i0 = blockIdx.x * 64;

    float acc[4][8];
#pragma unroll
    for (int r = 0; r < 4; ++r)
#pragma unroll
        for (int c = 0; c < 8; ++c) acc[r][c] = 0.0f;

    for (int k0 = 0; k0 < 256; k0 += 64) {
        __syncthreads();
        {
            int k4 = tid & 15, r0 = tid >> 4;
#pragma unroll
            for (int p = 0; p < 4; ++p) {
                int r = r0 + p * 16;
                *(float4*)&At[r][k4 * 4] =
                    *(const float4*)&A[(size_t)(i0 + r) * 256 + k0 + k4 * 4];
            }
        }
        {
            int c4 = tid & 31, kk0 = tid >> 5;
#pragma unroll
            for (int p = 0; p < 8; ++p) {
                int kk = kk0 + p * 8;
                *(float4*)&Wt[kk][c4 * 4] =
                    *(const float4*)&W[(size_t)(k0 + kk) * 128 + c4 * 4];
            }
        }
        __syncthreads();
#pragma unroll 4
        for (int kk = 0; kk < 64; ++kk) {
            float a[4];
#pragma unroll
            for (int r = 0; r < 4; ++r) a[r] = At[rowg * 4 + r][kk];
            const float4 w0 = *(const float4*)&Wt[kk][colg * 4];
            const float4 w1 = *(const float4*)&Wt[kk][64 + colg * 4];
            float w[8] = {w0.x, w0.y, w0.z, w0.w, w1.x, w1.y, w1.z, w1.w};
#pragma unroll
            for (int r = 0; r < 4; ++r)
#pragma unroll
                for (int c = 0; c < 8; ++c) acc[r][c] += a[r] * w[c];
        }
    }
    __syncthreads();   // done reading Wt; reuse as g1 tile [64][128]
    float* g1s = &Wt[0][0];
    // stage fc2W (128x12) into At space
    float* w2s = &At[0][0];
    for (int idx = tid; idx < 128 * 12; idx += 256) w2s[idx] = fc2W[idx];

#pragma unroll
    for (int r = 0; r < 4; ++r) {
        int row = rowg * 4 + r;
#pragma unroll
        for (int h = 0; h < 2; ++h) {
            int j = h * 64 + colg * 4;
            const float4 b = *(const float4*)&bias[j];
            float4 v;
            v.x = fmaxf(acc[r][h * 4 + 0] + b.x, 0.f);
            v.y = fmaxf(acc[r][h * 4 + 1] + b.y, 0.f);
            v.z = fmaxf(acc[r][h * 4 + 2] + b.z, 0.f);
            v.w = fmaxf(acc[r][h * 4 + 3] + b.w, 0.f);
            *(float4*)&g1s[row * 128 + j] = v;
        }
    }
    __syncthreads();
    // out tile 64 x 12
    for (int idx = tid; idx < 64 * 12; idx += 256) {
        int row = idx / 12, col = idx % 12;
        float o = fc2b[col];
        const float* gr = &g1s[row * 128];
        for (int k = 0; k < 128; ++k) o += gr[k] * w2s[k * 12 + col];
        out[(size_t)(i0 + row) * 12 + col] = o;
    }
}

// ---------- Y_g = mean_{i in g}(Â r)_i — MLP-unrolled flat loops ----------
__global__ __launch_bounds__(256) void k_pool(const float* __restrict__ r,
                                              const float* __restrict__ dinv,
                                              const int* __restrict__ rowptr,
                                              const int* __restrict__ ecol,
                                              const float* __restrict__ ecoef,
                                              const int* __restrict__ batch,
                                              float* __restrict__ Y,
                                              float* __restrict__ cntf) {
    int g = blockIdx.x, tid = threadIdx.x;
    // batch sorted: binary search node range [lo, hi)
    int l = 0, rr = NN;
    while (l < rr) { int m = (l + rr) >> 1; if (batch[m] < g) l = m + 1; else rr = m; }
    int lo = l;
    rr = NN;
    while (l < rr) { int m = (l + rr) >> 1; if (batch[m] < g + 1) l = m + 1; else rr = m; }
    int hi = l;
    int cnt = hi - lo;

    int lane = tid & 31, ty = tid >> 5;
    int c = lane * 4;
    float4 acc = {0.f, 0.f, 0.f, 0.f};

    // self terms, unroll x2
    int i = lo + ty;
    for (; i + 8 < hi; i += 16) {
        float d0 = dinv[i], d1 = dinv[i + 8];
        const float4 v0 = *(const float4*)&r[(size_t)i * 128 + c];
        const float4 v1 = *(const float4*)&r[(size_t)(i + 8) * 128 + c];
        float w0 = d0 * d0, w1 = d1 * d1;
        acc.x += v0.x * w0 + v1.x * w1;
        acc.y += v0.y * w0 + v1.y * w1;
        acc.z += v0.z * w0 + v1.z * w1;
        acc.w += v0.w * w0 + v1.w * w1;
    }
    for (; i < hi; i += 8) {
        float di = dinv[i], d2 = di * di;
        const float4 v = *(const float4*)&r[(size_t)i * 128 + c];
        acc.x += v.x * d2; acc.y += v.y * d2; acc.z += v.z * d2; acc.w += v.w * d2;
    }

    // edge terms (contiguous slot range), unroll x4 for MLP
    int e0 = rowptr[lo], e1 = rowptr[hi];
    int e = e0 + ty;
    for (; e + 24 < e1; e += 32) {
        int s0 = ecol[e], s1 = ecol[e + 8], s2 = ecol[e + 16], s3 = ecol[e + 24];
        float w0 = ecoef[e], w1 = ecoef[e + 8], w2 = ecoef[e + 16], w3 = ecoef[e + 24];
        const float4 v0 = *(const float4*)&r[(size_t)s0 * 128 + c];
        const float4 v1 = *(const float4*)&r[(size_t)s1 * 128 + c];
        const float4 v2 = *(const float4*)&r[(size_t)s2 * 128 + c];
        const float4 v3 = *(const float4*)&r[(size_t)s3 * 128 + c];
        acc.x += v0.x * w0 + v1.x * w1 + v2.x * w2 + v3.x * w3;
        acc.y += v0.y * w0 + v1.y * w1 + v2.y * w2 + v3.y * w3;
        acc.z += v0.z * w0 + v1.z * w1 + v2.z * w2 + v3.z * w3;
        acc.w += v0.w * w0 + v1.w * w1 + v2.w * w2 + v3.w * w3;
    }
    for (; e < e1; e += 8) {
        int s = ecol[e];
        float w = ecoef[e];
        const float4 v = *(const float4*)&r[(size_t)s * 128 + c];
        acc.x += v.x * w; acc.y += v.y * w; acc.z += v.z * w; acc.w += v.w * w;
    }

    __shared__ float red[8][128];
    *(float4*)&red[ty][c] = acc;
    __syncthreads();
    if (tid < 128) {
        float s = 0.0f;
#pragma unroll
        for (int t = 0; t < 8; ++t) s += red[t][tid];
        float inv = (cnt > 0) ? 1.0f / (float)cnt : 0.0f;
        Y[(size_t)g * 128 + tid] = s * inv;
    }
    if (tid == 0) cntf[g] = (float)cnt;
}

extern "C" void kernel_launch(void* const* d_in, const int* in_sizes, int n_in,
                              void* d_out, int out_size, void* d_ws, size_t ws_size,
                              hipStream_t stream) {
    const float* x     = (const float*)d_in[0];
    const int*   ei    = (const int*)d_in[1];
    const int*   batch = (const int*)d_in[2];
    const float* W1    = (const float*)d_in[3];
    const float* b1    = (const float*)d_in[4];
    const float* W2    = (const float*)d_in[5];
    const float* b2    = (const float*)d_in[6];
    const float* W3    = (const float*)d_in[7];
    const float* b3    = (const float*)d_in[8];
    const float* fc1W  = (const float*)d_in[9];
    const float* fc1b  = (const float*)d_in[10];
    const float* fc2W  = (const float*)d_in[11];
    const float* fc2b  = (const float*)d_in[12];
    float* out = (float*)d_out;

    const int* srcp = ei;        // edge_index[0]
    const int* dstp = ei + EE;   // edge_index[1]

    // workspace layout (~75 MB)
    float* r      = (float*)d_ws;                  // N*128
    float* Y      = r + (size_t)NN * 128;          // G*128
    float* pooled = Y + (size_t)GG * 128;          // G*256
    float* cntf   = pooled + (size_t)GG * 256;     // G
    float* dinv   = cntf + GG;                     // N
    float* zbuf   = dinv + NN;                     // N
    float* ecoef  = zbuf + NN;                     // E
    int* indeg  = (int*)(ecoef + EE);              // N
    int* rowptr = indeg + NN;                      // N+4
    int* cursor = rowptr + NN + 4;                 // N
    int* ecol   = cursor + NN;                     // E
    int* bsum   = ecol + EE;                       // 512
    int* boff   = bsum + 512;                      // 513

    // CSR build
    hipMemsetAsync(indeg, 0, NN * sizeof(int), stream);
    k_count<<<EE / 256, 256, 0, stream>>>(dstp, indeg);
    k_scan_a<<<NN / 256, 256, 0, stream>>>(indeg, bsum, dinv);
    k_scan_b<<<1, 512, 0, stream>>>(bsum, boff);
    k_scan_c<<<NN / 256, 256, 0, stream>>>(indeg, boff, rowptr, cursor);
    k_fill_edges<<<EE / 256, 256, 0, stream>>>(srcp, dstp, dinv, cursor, ecol, ecoef);

    // conv1 scalar
    k_z<<<NN / 256, 256, 0, stream>>>(x, dinv, rowptr, ecol, ecoef, zbuf);

    // conv2 fused: r = relu([Â relu(z⊗W1+b1)] @ W2 + b2)
    k_gemm2u<<<NN / 64, 256, 0, stream>>>(zbuf, dinv, rowptr, ecol, ecoef,
                                          W1, b1, W2, b2, r);

    // conv3 aggregation + mean pool
    k_pool<<<GG, 256, 0, stream>>>(r, dinv, rowptr, ecol, ecoef, batch, Y, cntf);

    // head: pooled = Y@W3+b3 (guarded), then fused fc1+fc2
    k_gemm<128, 256, false, true><<<dim3(GG / 64, 2), 256, 0, stream>>>(
        Y, W3, b3, cntf, pooled);
    k_fc12<<<GG / 64, 256, 0, stream>>>(pooled, fc1W, fc1b, fc2W, fc2b, out);
}

// Round 8
// 155.628 us; speedup vs baseline: 6.8026x; 1.0161x over previous
//
#include <hip/hip_runtime.h>

#define NN 131072   // nodes
#define EE 262144   // edges
#define GG 4096     // graphs

// ---------- CSR build ----------
__global__ void k_count(const int* __restrict__ dst, int* __restrict__ indeg) {
    int e = blockIdx.x * 256 + threadIdx.x;
    if (e < EE) atomicAdd(&indeg[dst[e]], 1);
}

// A: per-block (256 elems) totals + dinv + gstart from sorted batch
__global__ __launch_bounds__(256) void k_scan_a(const int* __restrict__ indeg,
                                                int* __restrict__ bsum,
                                                float* __restrict__ dinv,
                                                const int* __restrict__ batch,
                                                int* __restrict__ gstart) {
    __shared__ int red[256];
    int tid = threadIdx.x;
    int gid = blockIdx.x * 256 + tid;
    int v = indeg[gid];
    dinv[gid] = rsqrtf((float)v + 1.0f);
    red[tid] = v;
    // graph starts: batch sorted; set gstart[g]=gid for all g in (batch[gid-1], batch[gid]]
    {
        int b1v = batch[gid];
        int b0v = (gid == 0) ? -1 : batch[gid - 1];
        for (int g = b0v + 1; g <= b1v; ++g) gstart[g] = gid;
        if (gid == NN - 1)
            for (int g = b1v + 1; g <= GG; ++g) gstart[g] = NN;
    }
    __syncthreads();
#pragma unroll
    for (int off = 128; off > 0; off >>= 1) {
        if (tid < off) red[tid] += red[tid + off];
        __syncthreads();
    }
    if (tid == 0) bsum[blockIdx.x] = red[0];
}

// B: single block, exclusive scan of bsum[512] -> boff[513]
__global__ __launch_bounds__(512) void k_scan_b(const int* __restrict__ bsum,
                                                int* __restrict__ boff) {
    __shared__ int ps[512];
    int tid = threadIdx.x;
    ps[tid] = bsum[tid];
    __syncthreads();
    for (int off = 1; off < 512; off <<= 1) {
        int v = (tid >= off) ? ps[tid - off] : 0;
        __syncthreads();
        ps[tid] += v;
        __syncthreads();
    }
    boff[tid] = (tid > 0) ? ps[tid - 1] : 0;
    if (tid == 511) boff[512] = ps[511];
}

// C: per-block local exclusive scan + block offset -> rowptr & cursor
__global__ __launch_bounds__(256) void k_scan_c(const int* __restrict__ indeg,
                                                const int* __restrict__ boff,
                                                int* __restrict__ rowptr,
                                                int* __restrict__ cursor) {
    __shared__ int ps[256];
    int tid = threadIdx.x;
    int gid = blockIdx.x * 256 + tid;
    int v = indeg[gid];
    ps[tid] = v;
    __syncthreads();
    for (int off = 1; off < 256; off <<= 1) {
        int t = (tid >= off) ? ps[tid - off] : 0;
        __syncthreads();
        ps[tid] += t;
        __syncthreads();
    }
    int excl = boff[blockIdx.x] + ps[tid] - v;
    rowptr[gid] = excl;
    cursor[gid] = excl;
    if (gid == NN - 1) rowptr[NN] = boff[512];
}

// fill ecol + per-slot coefficient ecoef = dinv[d]*dinv[s]
__global__ void k_fill_edges(const int* __restrict__ src, const int* __restrict__ dst,
                             const float* __restrict__ dinv,
                             int* __restrict__ cursor, int* __restrict__ ecol,
                             float* __restrict__ ecoef) {
    int e = blockIdx.x * 256 + threadIdx.x;
    if (e < EE) {
        int d = dst[e], s = src[e];
        int slot = atomicAdd(&cursor[d], 1);
        ecol[slot] = s;
        ecoef[slot] = dinv[d] * dinv[s];
    }
}

// ---------- conv1 scalar: z[i] = x_i*dinv_i^2 + sum_e ecoef[e]*x[ecol[e]] ----------
__global__ void k_z(const float* __restrict__ x, const float* __restrict__ dinv,
                    const int* __restrict__ rowptr, const int* __restrict__ ecol,
                    const float* __restrict__ ecoef, float* __restrict__ z) {
    int i = blockIdx.x * 256 + threadIdx.x;
    if (i < NN) {
        float di = dinv[i];
        float s = x[i] * di * di;
        int e0 = rowptr[i], e1 = rowptr[i + 1];
        for (int e = e0; e < e1; ++e) s += ecoef[e] * x[ecol[e]];
        z[i] = s;
    }
}

// ---------- fused conv2: r = relu( [Â relu(z⊗W1+b1)] @ W2 + b2 ) ----------
// LDS: At[64][65] (pad 65 -> 2-way write conflicts = free) + Wt[32][128] (2 K-chunks)
// total ~33.6KB -> 4 blocks/CU.
__global__ __launch_bounds__(256) void k_gemm2u(const float* __restrict__ z,
                                                const float* __restrict__ dinv,
                                                const int* __restrict__ rowptr,
                                                const int* __restrict__ ecol,
                                                const float* __restrict__ ecoef,
                                                const float* __restrict__ W1,
                                                const float* __restrict__ b1,
                                                const float* __restrict__ W2,
                                                const float* __restrict__ b2,
                                                float* __restrict__ r) {
    __shared__ float At[64][65];
    __shared__ float Wt[32][128];
    __shared__ float w1s[64], b1s[64];

    int tid = threadIdx.x;
    int i0 = blockIdx.x * 64;

    if (tid < 64) { w1s[tid] = W1[tid]; b1s[tid] = b1[tid]; }
    __syncthreads();

    {   // generate u rows: 4 threads per node, 16 k's each
        int n = tid >> 2;
        int k0 = (tid & 3) * 16;
        int i = i0 + n;
        float zi = z[i], di = dinv[i];
        float d2 = di * di;
        float uacc[16];
#pragma unroll
        for (int j = 0; j < 16; ++j)
            uacc[j] = d2 * fmaxf(zi * w1s[k0 + j] + b1s[k0 + j], 0.f);
        int e0 = rowptr[i], e1 = rowptr[i + 1];
        for (int e = e0; e < e1; ++e) {
            float w = ecoef[e];
            float zs = z[ecol[e]];
#pragma unroll
            for (int j = 0; j < 16; ++j)
                uacc[j] += w * fmaxf(zs * w1s[k0 + j] + b1s[k0 + j], 0.f);
        }
#pragma unroll
        for (int j = 0; j < 16; ++j) At[n][k0 + j] = uacc[j];
    }

    int colg = tid & 15;
    int rowg = tid >> 4;
    float acc[4][8];
#pragma unroll
    for (int rr = 0; rr < 4; ++rr)
#pragma unroll
        for (int c = 0; c < 8; ++c) acc[rr][c] = 0.0f;

    for (int kc = 0; kc < 2; ++kc) {
        if (kc) __syncthreads();   // protect Wt before restage
        {   // stage Wt rows kc*32 .. kc*32+31
            int c4 = tid & 31, kk0 = tid >> 5;
#pragma unroll
            for (int p = 0; p < 4; ++p) {
                int kk = kk0 + p * 8;
                *(float4*)&Wt[kk][c4 * 4] =
                    *(const float4*)&W2[(size_t)(kc * 32 + kk) * 128 + c4 * 4];
            }
        }
        __syncthreads();           // At (first iter) + Wt ready
#pragma unroll 4
        for (int kk = 0; kk < 32; ++kk) {
            float a[4];
#pragma unroll
            for (int rr = 0; rr < 4; ++rr) a[rr] = At[rowg * 4 + rr][kc * 32 + kk];
            const float4 w0 = *(const float4*)&Wt[kk][colg * 4];
            const float4 w1 = *(const float4*)&Wt[kk][64 + colg * 4];
            float w[8] = {w0.x, w0.y, w0.z, w0.w, w1.x, w1.y, w1.z, w1.w};
#pragma unroll
            for (int rr = 0; rr < 4; ++rr)
#pragma unroll
                for (int c = 0; c < 8; ++c) acc[rr][c] += a[rr] * w[c];
        }
    }

#pragma unroll
    for (int rr = 0; rr < 4; ++rr) {
        int i = i0 + rowg * 4 + rr;
#pragma unroll
        for (int h = 0; h < 2; ++h) {
            int j = h * 64 + colg * 4;
            const float4 b = *(const float4*)&b2[j];
            float4 v;
            v.x = fmaxf(acc[rr][h * 4 + 0] + b.x, 0.f);
            v.y = fmaxf(acc[rr][h * 4 + 1] + b.y, 0.f);
            v.z = fmaxf(acc[rr][h * 4 + 2] + b.z, 0.f);
            v.w = fmaxf(acc[rr][h * 4 + 3] + b.w, 0.f);
            *(float4*)&r[(size_t)i * 128 + j] = v;
        }
    }
}

// ---------- Y_g = mean_{i in g}(Â r)_i — gstart-indexed flat loops ----------
__global__ __launch_bounds__(256) void k_pool(const float* __restrict__ r,
                                              const float* __restrict__ dinv,
                                              const int* __restrict__ rowptr,
                                              const int* __restrict__ ecol,
                                              const float* __restrict__ ecoef,
                                              const int* __restrict__ gstart,
                                              float* __restrict__ Y,
                                              float* __restrict__ cntf) {
    int g = blockIdx.x, tid = threadIdx.x;
    int lo = gstart[g], hi = gstart[g + 1];
    int cnt = hi - lo;

    int lane = tid & 31, ty = tid >> 5;
    int c = lane * 4;
    float4 acc = {0.f, 0.f, 0.f, 0.f};

    // self terms, unroll x2
    int i = lo + ty;
    for (; i + 8 < hi; i += 16) {
        float d0 = dinv[i], d1 = dinv[i + 8];
        const float4 v0 = *(const float4*)&r[(size_t)i * 128 + c];
        const float4 v1 = *(const float4*)&r[(size_t)(i + 8) * 128 + c];
        float w0 = d0 * d0, w1 = d1 * d1;
        acc.x += v0.x * w0 + v1.x * w1;
        acc.y += v0.y * w0 + v1.y * w1;
        acc.z += v0.z * w0 + v1.z * w1;
        acc.w += v0.w * w0 + v1.w * w1;
    }
    for (; i < hi; i += 8) {
        float di = dinv[i], d2 = di * di;
        const float4 v = *(const float4*)&r[(size_t)i * 128 + c];
        acc.x += v.x * d2; acc.y += v.y * d2; acc.z += v.z * d2; acc.w += v.w * d2;
    }

    // edge terms (contiguous slot range), unroll x4
    int e0 = rowptr[lo], e1 = rowptr[hi];
    int e = e0 + ty;
    for (; e + 24 < e1; e += 32) {
        int s0 = ecol[e], s1 = ecol[e + 8], s2 = ecol[e + 16], s3 = ecol[e + 24];
        float w0 = ecoef[e], w1 = ecoef[e + 8], w2 = ecoef[e + 16], w3 = ecoef[e + 24];
        const float4 v0 = *(const float4*)&r[(size_t)s0 * 128 + c];
        const float4 v1 = *(const float4*)&r[(size_t)s1 * 128 + c];
        const float4 v2 = *(const float4*)&r[(size_t)s2 * 128 + c];
        const float4 v3 = *(const float4*)&r[(size_t)s3 * 128 + c];
        acc.x += v0.x * w0 + v1.x * w1 + v2.x * w2 + v3.x * w3;
        acc.y += v0.y * w0 + v1.y * w1 + v2.y * w2 + v3.y * w3;
        acc.z += v0.z * w0 + v1.z * w1 + v2.z * w2 + v3.z * w3;
        acc.w += v0.w * w0 + v1.w * w1 + v2.w * w2 + v3.w * w3;
    }
    for (; e < e1; e += 8) {
        int s = ecol[e];
        float w = ecoef[e];
        const float4 v = *(const float4*)&r[(size_t)s * 128 + c];
        acc.x += v.x * w; acc.y += v.y * w; acc.z += v.z * w; acc.w += v.w * w;
    }

    __shared__ float red[8][128];
    *(float4*)&red[ty][c] = acc;
    __syncthreads();
    if (tid < 128) {
        float s = 0.0f;
#pragma unroll
        for (int t = 0; t < 8; ++t) s += red[t][tid];
        float inv = (cnt > 0) ? 1.0f / (float)cnt : 0.0f;
        Y[(size_t)g * 128 + tid] = s * inv;
    }
    if (tid == 0) cntf[g] = (float)cnt;
}

// ---------- fused head: pooled = Y@W3 + b3*flag ; g1 = relu(pooled@fc1W+fc1b); out = g1@fc2W+fc2b ----------
__global__ __launch_bounds__(256) void k_head3(const float* __restrict__ Y,
                                               const float* __restrict__ cntf,
                                               const float* __restrict__ W3,
                                               const float* __restrict__ b3,
                                               const float* __restrict__ fc1W,
                                               const float* __restrict__ fc1b,
                                               const float* __restrict__ fc2W,
                                               const float* __restrict__ fc2b,
                                               float* __restrict__ out) {
    __shared__ float At[64][68];
    __shared__ float Wt[64][128];
    __shared__ float pS[64][260];   // pooled tile, stride 260 ≡ 4 (mod 32)

    int tid  = threadIdx.x;
    int colg = tid & 15;
    int rowg = tid >> 4;
    int i0 = blockIdx.x * 64;

    // phase 1: pS = Y @ W3 + b3*flag   (K=128, OUT=256 in two 128-col halves)
    for (int jh = 0; jh < 2; ++jh) {
        float acc[4][8];
#pragma unroll
        for (int rr = 0; rr < 4; ++rr)
#pragma unroll
            for (int c = 0; c < 8; ++c) acc[rr][c] = 0.0f;

        for (int k0 = 0; k0 < 128; k0 += 64) {
            __syncthreads();
            {
                int k4 = tid & 15, r0 = tid >> 4;
#pragma unroll
                for (int p = 0; p < 4; ++p) {
                    int rr = r0 + p * 16;
                    *(float4*)&At[rr][k4 * 4] =
                        *(const float4*)&Y[(size_t)(i0 + rr) * 128 + k0 + k4 * 4];
                }
            }
            {
                int c4 = tid & 31, kk0 = tid >> 5;
#pragma unroll
                for (int p = 0; p < 8; ++p) {
                    int kk = kk0 + p * 8;
                    *(float4*)&Wt[kk][c4 * 4] =
                        *(const float4*)&W3[(size_t)(k0 + kk) * 256 + jh * 128 + c4 * 4];
                }
            }
            __syncthreads();
#pragma unroll 4
            for (int kk = 0; kk < 64; ++kk) {
                float a[4];
#pragma unroll
                for (int rr = 0; rr < 4; ++rr) a[rr] = At[rowg * 4 + rr][kk];
                const float4 w0 = *(const float4*)&Wt[kk][colg * 4];
                const float4 w1 = *(const float4*)&Wt[kk][64 + colg * 4];
                float w[8] = {w0.x, w0.y, w0.z, w0.w, w1.x, w1.y, w1.z, w1.w};
#pragma unroll
                for (int rr = 0; rr < 4; ++rr)
#pragma unroll
                    for (int c = 0; c < 8; ++c) acc[rr][c] += a[rr] * w[c];
            }
        }
#pragma unroll
        for (int rr = 0; rr < 4; ++rr) {
            int row = rowg * 4 + rr;
            float flag = (cntf[i0 + row] > 0.0f) ? 1.0f : 0.0f;
#pragma unroll
            for (int h = 0; h < 2; ++h) {
                int j = jh * 128 + h * 64 + colg * 4;
                const float4 b = *(const float4*)&b3[j];
                pS[row][j + 0] = acc[rr][h * 4 + 0] + b.x * flag;
                pS[row][j + 1] = acc[rr][h * 4 + 1] + b.y * flag;
                pS[row][j + 2] = acc[rr][h * 4 + 2] + b.z * flag;
                pS[row][j + 3] = acc[rr][h * 4 + 3] + b.w * flag;
            }
        }
    }
    __syncthreads();   // pS complete; everyone done with At/Wt

    // phase 2: g1 = relu(pS @ fc1W + fc1b)   (K=256, OUT=128), A read from pS
    float acc[4][8];
#pragma unroll
    for (int rr = 0; rr < 4; ++rr)
#pragma unroll
        for (int c = 0; c < 8; ++c) acc[rr][c] = 0.0f;

    for (int k0 = 0; k0 < 256; k0 += 64) {
        if (k0) __syncthreads();
        {
            int c4 = tid & 31, kk0 = tid >> 5;
#pragma unroll
            for (int p = 0; p < 8; ++p) {
                int kk = kk0 + p * 8;
                *(float4*)&Wt[kk][c4 * 4] =
                    *(const float4*)&fc1W[(size_t)(k0 + kk) * 128 + c4 * 4];
            }
        }
        __syncthreads();
#pragma unroll 4
        for (int kk = 0; kk < 64; ++kk) {
            float a[4];
#pragma unroll
            for (int rr = 0; rr < 4; ++rr) a[rr] = pS[rowg * 4 + rr][k0 + kk];
            const float4 w0 = *(const float4*)&Wt[kk][colg * 4];
            const float4 w1 = *(const float4*)&Wt[kk][64 + colg * 4];
            float w[8] = {w0.x, w0.y, w0.z, w0.w, w1.x, w1.y, w1.z, w1.w};
#pragma unroll
            for (int rr = 0; rr < 4; ++rr)
#pragma unroll
                for (int c = 0; c < 8; ++c) acc[rr][c] += a[rr] * w[c];
        }
    }
    __syncthreads();   // done reading Wt(fc1W)

    // g1 tile into Wt; fc2W into At space
    float* g1s = &Wt[0][0];
    float* w2s = &At[0][0];
#pragma unroll
    for (int rr = 0; rr < 4; ++rr) {
        int row = rowg * 4 + rr;
#pragma unroll
        for (int h = 0; h < 2; ++h) {
            int j = h * 64 + colg * 4;
            const float4 b = *(const float4*)&fc1b[j];
            float4 v;
            v.x = fmaxf(acc[rr][h * 4 + 0] + b.x, 0.f);
            v.y = fmaxf(acc[rr][h * 4 + 1] + b.y, 0.f);
            v.z = fmaxf(acc[rr][h * 4 + 2] + b.z, 0.f);
            v.w = fmaxf(acc[rr][h * 4 + 3] + b.w, 0.f);
            *(float4*)&g1s[row * 128 + j] = v;
        }
    }
    for (int idx = tid; idx < 128 * 12; idx += 256) w2s[idx] = fc2W[idx];
    __syncthreads();

    // out tile 64 x 12
    for (int idx = tid; idx < 64 * 12; idx += 256) {
        int row = idx / 12, col = idx % 12;
        float o = fc2b[col];
        const float* gr = &g1s[row * 128];
        for (int k = 0; k < 128; ++k) o += gr[k] * w2s[k * 12 + col];
        out[(size_t)(i0 + row) * 12 + col] = o;
    }
}

extern "C" void kernel_launch(void* const* d_in, const int* in_sizes, int n_in,
                              void* d_out, int out_size, void* d_ws, size_t ws_size,
                              hipStream_t stream) {
    const float* x     = (const float*)d_in[0];
    const int*   ei    = (const int*)d_in[1];
    const int*   batch = (const int*)d_in[2];
    const float* W1    = (const float*)d_in[3];
    const float* b1    = (const float*)d_in[4];
    const float* W2    = (const float*)d_in[5];
    const float* b2    = (const float*)d_in[6];
    const float* W3    = (const float*)d_in[7];
    const float* b3    = (const float*)d_in[8];
    const float* fc1W  = (const float*)d_in[9];
    const float* fc1b  = (const float*)d_in[10];
    const float* fc2W  = (const float*)d_in[11];
    const float* fc2b  = (const float*)d_in[12];
    float* out = (float*)d_out;

    const int* srcp = ei;        // edge_index[0]
    const int* dstp = ei + EE;   // edge_index[1]

    // workspace layout (~75 MB)
    float* r      = (float*)d_ws;                  // N*128
    float* Y      = r + (size_t)NN * 128;          // G*128
    float* cntf   = Y + (size_t)GG * 128;          // G
    float* dinv   = cntf + GG;                     // N
    float* zbuf   = dinv + NN;                     // N
    float* ecoef  = zbuf + NN;                     // E
    int* indeg  = (int*)(ecoef + EE);              // N
    int* rowptr = indeg + NN;                      // N+4
    int* cursor = rowptr + NN + 4;                 // N
    int* ecol   = cursor + NN;                     // E
    int* bsum   = ecol + EE;                       // 512
    int* boff   = bsum + 512;                      // 513
    int* gstart = boff + 516;                      // G+1

    // CSR build (+ dinv, gstart folded into scan_a)
    hipMemsetAsync(indeg, 0, NN * sizeof(int), stream);
    k_count<<<EE / 256, 256, 0, stream>>>(dstp, indeg);
    k_scan_a<<<NN / 256, 256, 0, stream>>>(indeg, bsum, dinv, batch, gstart);
    k_scan_b<<<1, 512, 0, stream>>>(bsum, boff);
    k_scan_c<<<NN / 256, 256, 0, stream>>>(indeg, boff, rowptr, cursor);
    k_fill_edges<<<EE / 256, 256, 0, stream>>>(srcp, dstp, dinv, cursor, ecol, ecoef);

    // conv1 scalar
    k_z<<<NN / 256, 256, 0, stream>>>(x, dinv, rowptr, ecol, ecoef, zbuf);

    // conv2 fused: r = relu([Â relu(z⊗W1+b1)] @ W2 + b2)
    k_gemm2u<<<NN / 64, 256, 0, stream>>>(zbuf, dinv, rowptr, ecol, ecoef,
                                          W1, b1, W2, b2, r);

    // conv3 aggregation + mean pool
    k_pool<<<GG, 256, 0, stream>>>(r, dinv, rowptr, ecol, ecoef, gstart, Y, cntf);

    // fused head
    k_head3<<<GG / 64, 256, 0, stream>>>(Y, cntf, W3, b3, fc1W, fc1b,
                                         fc2W, fc2b, out);
}

// Round 9
// 148.610 us; speedup vs baseline: 7.1239x; 1.0472x over previous
//
#include <hip/hip_runtime.h>

#define NN 131072   // nodes
#define EE 262144   // edges
#define GG 4096     // graphs

// ---------- CSR build ----------
__global__ void k_count(const int* __restrict__ dst, int* __restrict__ indeg) {
    int e = blockIdx.x * 256 + threadIdx.x;
    if (e < EE) atomicAdd(&indeg[dst[e]], 1);
}

// A: per-block (256 elems) totals + dinv + gstart from sorted batch
__global__ __launch_bounds__(256) void k_scan_a(const int* __restrict__ indeg,
                                                int* __restrict__ bsum,
                                                float* __restrict__ dinv,
                                                const int* __restrict__ batch,
                                                int* __restrict__ gstart) {
    __shared__ int red[256];
    int tid = threadIdx.x;
    int gid = blockIdx.x * 256 + tid;
    int v = indeg[gid];
    dinv[gid] = rsqrtf((float)v + 1.0f);
    red[tid] = v;
    {
        int b1v = batch[gid];
        int b0v = (gid == 0) ? -1 : batch[gid - 1];
        for (int g = b0v + 1; g <= b1v; ++g) gstart[g] = gid;
        if (gid == NN - 1)
            for (int g = b1v + 1; g <= GG; ++g) gstart[g] = NN;
    }
    __syncthreads();
#pragma unroll
    for (int off = 128; off > 0; off >>= 1) {
        if (tid < off) red[tid] += red[tid + off];
        __syncthreads();
    }
    if (tid == 0) bsum[blockIdx.x] = red[0];
}

// B: single block, exclusive scan of bsum[512] -> boff[513]
__global__ __launch_bounds__(512) void k_scan_b(const int* __restrict__ bsum,
                                                int* __restrict__ boff) {
    __shared__ int ps[512];
    int tid = threadIdx.x;
    ps[tid] = bsum[tid];
    __syncthreads();
    for (int off = 1; off < 512; off <<= 1) {
        int v = (tid >= off) ? ps[tid - off] : 0;
        __syncthreads();
        ps[tid] += v;
        __syncthreads();
    }
    boff[tid] = (tid > 0) ? ps[tid - 1] : 0;
    if (tid == 511) boff[512] = ps[511];
}

// C: per-block local exclusive scan + block offset -> rowptr & cursor
__global__ __launch_bounds__(256) void k_scan_c(const int* __restrict__ indeg,
                                                const int* __restrict__ boff,
                                                int* __restrict__ rowptr,
                                                int* __restrict__ cursor) {
    __shared__ int ps[256];
    int tid = threadIdx.x;
    int gid = blockIdx.x * 256 + tid;
    int v = indeg[gid];
    ps[tid] = v;
    __syncthreads();
    for (int off = 1; off < 256; off <<= 1) {
        int t = (tid >= off) ? ps[tid - off] : 0;
        __syncthreads();
        ps[tid] += t;
        __syncthreads();
    }
    int excl = boff[blockIdx.x] + ps[tid] - v;
    rowptr[gid] = excl;
    cursor[gid] = excl;
    if (gid == NN - 1) rowptr[NN] = boff[512];
}

// fill ecol + per-slot coefficient ecoef = dinv[d]*dinv[s]
__global__ void k_fill_edges(const int* __restrict__ src, const int* __restrict__ dst,
                             const float* __restrict__ dinv,
                             int* __restrict__ cursor, int* __restrict__ ecol,
                             float* __restrict__ ecoef) {
    int e = blockIdx.x * 256 + threadIdx.x;
    if (e < EE) {
        int d = dst[e], s = src[e];
        int slot = atomicAdd(&cursor[d], 1);
        ecol[slot] = s;
        ecoef[slot] = dinv[d] * dinv[s];
    }
}

// ---------- conv1 scalar: z[i] = x_i*dinv_i^2 + sum_e ecoef[e]*x[ecol[e]] ----------
__global__ void k_z(const float* __restrict__ x, const float* __restrict__ dinv,
                    const int* __restrict__ rowptr, const int* __restrict__ ecol,
                    const float* __restrict__ ecoef, float* __restrict__ z) {
    int i = blockIdx.x * 256 + threadIdx.x;
    if (i < NN) {
        float di = dinv[i];
        float s = x[i] * di * di;
        int e0 = rowptr[i], e1 = rowptr[i + 1];
        for (int e = e0; e < e1; ++e) s += ecoef[e] * x[ecol[e]];
        z[i] = s;
    }
}

// ---------- fused conv2: r = relu( [Â relu(z⊗W1+b1)] @ W2 + b2 ) ----------
// LDS ~33.6KB -> 4 blocks/CU.
__global__ __launch_bounds__(256) void k_gemm2u(const float* __restrict__ z,
                                                const float* __restrict__ dinv,
                                                const int* __restrict__ rowptr,
                                                const int* __restrict__ ecol,
                                                const float* __restrict__ ecoef,
                                                const float* __restrict__ W1,
                                                const float* __restrict__ b1,
                                                const float* __restrict__ W2,
                                                const float* __restrict__ b2,
                                                float* __restrict__ r) {
    __shared__ float At[64][65];
    __shared__ float Wt[32][128];
    __shared__ float w1s[64], b1s[64];

    int tid = threadIdx.x;
    int i0 = blockIdx.x * 64;

    if (tid < 64) { w1s[tid] = W1[tid]; b1s[tid] = b1[tid]; }
    __syncthreads();

    {   // generate u rows: 4 threads per node, 16 k's each
        int n = tid >> 2;
        int k0 = (tid & 3) * 16;
        int i = i0 + n;
        float zi = z[i], di = dinv[i];
        float d2 = di * di;
        float uacc[16];
#pragma unroll
        for (int j = 0; j < 16; ++j)
            uacc[j] = d2 * fmaxf(zi * w1s[k0 + j] + b1s[k0 + j], 0.f);
        int e0 = rowptr[i], e1 = rowptr[i + 1];
        for (int e = e0; e < e1; ++e) {
            float w = ecoef[e];
            float zs = z[ecol[e]];
#pragma unroll
            for (int j = 0; j < 16; ++j)
                uacc[j] += w * fmaxf(zs * w1s[k0 + j] + b1s[k0 + j], 0.f);
        }
#pragma unroll
        for (int j = 0; j < 16; ++j) At[n][k0 + j] = uacc[j];
    }

    int colg = tid & 15;
    int rowg = tid >> 4;
    float acc[4][8];
#pragma unroll
    for (int rr = 0; rr < 4; ++rr)
#pragma unroll
        for (int c = 0; c < 8; ++c) acc[rr][c] = 0.0f;

    for (int kc = 0; kc < 2; ++kc) {
        if (kc) __syncthreads();
        {
            int c4 = tid & 31, kk0 = tid >> 5;
#pragma unroll
            for (int p = 0; p < 4; ++p) {
                int kk = kk0 + p * 8;
                *(float4*)&Wt[kk][c4 * 4] =
                    *(const float4*)&W2[(size_t)(kc * 32 + kk) * 128 + c4 * 4];
            }
        }
        __syncthreads();
#pragma unroll 4
        for (int kk = 0; kk < 32; ++kk) {
            float a[4];
#pragma unroll
            for (int rr = 0; rr < 4; ++rr) a[rr] = At[rowg * 4 + rr][kc * 32 + kk];
            const float4 w0 = *(const float4*)&Wt[kk][colg * 4];
            const float4 w1 = *(const float4*)&Wt[kk][64 + colg * 4];
            float w[8] = {w0.x, w0.y, w0.z, w0.w, w1.x, w1.y, w1.z, w1.w};
#pragma unroll
            for (int rr = 0; rr < 4; ++rr)
#pragma unroll
                for (int c = 0; c < 8; ++c) acc[rr][c] += a[rr] * w[c];
        }
    }

#pragma unroll
    for (int rr = 0; rr < 4; ++rr) {
        int i = i0 + rowg * 4 + rr;
#pragma unroll
        for (int h = 0; h < 2; ++h) {
            int j = h * 64 + colg * 4;
            const float4 b = *(const float4*)&b2[j];
            float4 v;
            v.x = fmaxf(acc[rr][h * 4 + 0] + b.x, 0.f);
            v.y = fmaxf(acc[rr][h * 4 + 1] + b.y, 0.f);
            v.z = fmaxf(acc[rr][h * 4 + 2] + b.z, 0.f);
            v.w = fmaxf(acc[rr][h * 4 + 3] + b.w, 0.f);
            *(float4*)&r[(size_t)i * 128 + j] = v;
        }
    }
}

// ---------- generic register-tiled GEMM: C = [relu](A @ W + bias[*flag]) ----------
template <int K, int OUTW, bool RELU_OUT, bool GUARD>
__global__ __launch_bounds__(256) void k_gemm(const float* __restrict__ A,
                                              const float* __restrict__ W,
                                              const float* __restrict__ bias,
                                              const float* __restrict__ cntf,
                                              float* __restrict__ C) {
    __shared__ float At[64][68];
    __shared__ float Wt[64][128];

    int tid  = threadIdx.x;
    int colg = tid & 15;
    int rowg = tid >> 4;
    int i0 = blockIdx.x * 64;
    int j0 = blockIdx.y * 128;

    float acc[4][8];
#pragma unroll
    for (int r = 0; r < 4; ++r)
#pragma unroll
        for (int c = 0; c < 8; ++c) acc[r][c] = 0.0f;

    for (int k0 = 0; k0 < K; k0 += 64) {
        __syncthreads();
        {
            int k4 = tid & 15, r0 = tid >> 4;
#pragma unroll
            for (int p = 0; p < 4; ++p) {
                int r = r0 + p * 16;
                *(float4*)&At[r][k4 * 4] =
                    *(const float4*)&A[(size_t)(i0 + r) * K + k0 + k4 * 4];
            }
        }
        {
            int c4 = tid & 31, kk0 = tid >> 5;
#pragma unroll
            for (int p = 0; p < 8; ++p) {
                int kk = kk0 + p * 8;
                *(float4*)&Wt[kk][c4 * 4] =
                    *(const float4*)&W[(size_t)(k0 + kk) * OUTW + j0 + c4 * 4];
            }
        }
        __syncthreads();
#pragma unroll 4
        for (int kk = 0; kk < 64; ++kk) {
            float a[4];
#pragma unroll
            for (int r = 0; r < 4; ++r) a[r] = At[rowg * 4 + r][kk];
            const float4 w0 = *(const float4*)&Wt[kk][colg * 4];
            const float4 w1 = *(const float4*)&Wt[kk][64 + colg * 4];
            float w[8] = {w0.x, w0.y, w0.z, w0.w, w1.x, w1.y, w1.z, w1.w};
#pragma unroll
            for (int r = 0; r < 4; ++r)
#pragma unroll
                for (int c = 0; c < 8; ++c) acc[r][c] += a[r] * w[c];
        }
    }

#pragma unroll
    for (int r = 0; r < 4; ++r) {
        int i = i0 + rowg * 4 + r;
        float flag = 1.0f;
        if (GUARD) flag = (cntf[i] > 0.0f) ? 1.0f : 0.0f;
#pragma unroll
        for (int h = 0; h < 2; ++h) {
            int j = j0 + h * 64 + colg * 4;
            const float4 b = *(const float4*)&bias[j];
            float4 v;
            v.x = acc[r][h * 4 + 0] + b.x * flag;
            v.y = acc[r][h * 4 + 1] + b.y * flag;
            v.z = acc[r][h * 4 + 2] + b.z * flag;
            v.w = acc[r][h * 4 + 3] + b.w * flag;
            if (RELU_OUT) {
                v.x = fmaxf(v.x, 0.f); v.y = fmaxf(v.y, 0.f);
                v.z = fmaxf(v.z, 0.f); v.w = fmaxf(v.w, 0.f);
            }
            *(float4*)&C[(size_t)i * OUTW + j] = v;
        }
    }
}

// ---------- fused head tail: g1 = relu(pooled @ fc1W + fc1b); out = g1 @ fc2W + fc2b ----------
__global__ __launch_bounds__(256) void k_fc12(const float* __restrict__ A,     // pooled G x 256
                                              const float* __restrict__ W,     // fc1W 256 x 128
                                              const float* __restrict__ bias,  // fc1b
                                              const float* __restrict__ fc2W,  // 128 x 12
                                              const float* __restrict__ fc2b,  // 12
                                              float* __restrict__ out) {
    __shared__ float At[64][68];
    __shared__ float Wt[64][128];    // reused as g1 tile after main loop

    int tid  = threadIdx.x;
    int colg = tid & 15;
    int rowg = tid >> 4;
    int i0 = blockIdx.x * 64;

    float acc[4][8];
#pragma unroll
    for (int r = 0; r < 4; ++r)
#pragma unroll
        for (int c = 0; c < 8; ++c) acc[r][c] = 0.0f;

    for (int k0 = 0; k0 < 256; k0 += 64) {
        __syncthreads();
        {
            int k4 = tid & 15, r0 = tid >> 4;
#pragma unroll
            for (int p = 0; p < 4; ++p) {
                int r = r0 + p * 16;
                *(float4*)&At[r][k4 * 4] =
                    *(const float4*)&A[(size_t)(i0 + r) * 256 + k0 + k4 * 4];
            }
        }
        {
            int c4 = tid & 31, kk0 = tid >> 5;
#pragma unroll
            for (int p = 0; p < 8; ++p) {
                int kk = kk0 + p * 8;
                *(float4*)&Wt[kk][c4 * 4] =
                    *(const float4*)&W[(size_t)(k0 + kk) * 128 + c4 * 4];
            }
        }
        __syncthreads();
#pragma unroll 4
        for (int kk = 0; kk < 64; ++kk) {
            float a[4];
#pragma unroll
            for (int r = 0; r < 4; ++r) a[r] = At[rowg * 4 + r][kk];
            const float4 w0 = *(const float4*)&Wt[kk][colg * 4];
            const float4 w1 = *(const float4*)&Wt[kk][64 + colg * 4];
            float w[8] = {w0.x, w0.y, w0.z, w0.w, w1.x, w1.y, w1.z, w1.w};
#pragma unroll
            for (int r = 0; r < 4; ++r)
#pragma unroll
                for (int c = 0; c < 8; ++c) acc[r][c] += a[r] * w[c];
        }
    }
    __syncthreads();   // done reading Wt; reuse as g1 tile [64][128]
    float* g1s = &Wt[0][0];
    float* w2s = &At[0][0];
    for (int idx = tid; idx < 128 * 12; idx += 256) w2s[idx] = fc2W[idx];

#pragma unroll
    for (int r = 0; r < 4; ++r) {
        int row = rowg * 4 + r;
#pragma unroll
        for (int h = 0; h < 2; ++h) {
            int j = h * 64 + colg * 4;
            const float4 b = *(const float4*)&bias[j];
            float4 v;
            v.x = fmaxf(acc[r][h * 4 + 0] + b.x, 0.f);
            v.y = fmaxf(acc[r][h * 4 + 1] + b.y, 0.f);
            v.z = fmaxf(acc[r][h * 4 + 2] + b.z, 0.f);
            v.w = fmaxf(acc[r][h * 4 + 3] + b.w, 0.f);
            *(float4*)&g1s[row * 128 + j] = v;
        }
    }
    __syncthreads();
    for (int idx = tid; idx < 64 * 12; idx += 256) {
        int row = idx / 12, col = idx % 12;
        float o = fc2b[col];
        const float* gr = &g1s[row * 128];
        for (int k = 0; k < 128; ++k) o += gr[k] * w2s[k * 12 + col];
        out[(size_t)(i0 + row) * 12 + col] = o;
    }
}

// ---------- Y_g = mean_{i in g}(Â r)_i — gstart-indexed flat loops ----------
__global__ __launch_bounds__(256) void k_pool(const float* __restrict__ r,
                                              const float* __restrict__ dinv,
                                              const int* __restrict__ rowptr,
                                              const int* __restrict__ ecol,
                                              const float* __restrict__ ecoef,
                                              const int* __restrict__ gstart,
                                              float* __restrict__ Y,
                                              float* __restrict__ cntf) {
    int g = blockIdx.x, tid = threadIdx.x;
    int lo = gstart[g], hi = gstart[g + 1];
    int cnt = hi - lo;

    int lane = tid & 31, ty = tid >> 5;
    int c = lane * 4;
    float4 acc = {0.f, 0.f, 0.f, 0.f};

    // self terms, unroll x2
    int i = lo + ty;
    for (; i + 8 < hi; i += 16) {
        float d0 = dinv[i], d1 = dinv[i + 8];
        const float4 v0 = *(const float4*)&r[(size_t)i * 128 + c];
        const float4 v1 = *(const float4*)&r[(size_t)(i + 8) * 128 + c];
        float w0 = d0 * d0, w1 = d1 * d1;
        acc.x += v0.x * w0 + v1.x * w1;
        acc.y += v0.y * w0 + v1.y * w1;
        acc.z += v0.z * w0 + v1.z * w1;
        acc.w += v0.w * w0 + v1.w * w1;
    }
    for (; i < hi; i += 8) {
        float di = dinv[i], d2 = di * di;
        const float4 v = *(const float4*)&r[(size_t)i * 128 + c];
        acc.x += v.x * d2; acc.y += v.y * d2; acc.z += v.z * d2; acc.w += v.w * d2;
    }

    // edge terms (contiguous slot range), unroll x4
    int e0 = rowptr[lo], e1 = rowptr[hi];
    int e = e0 + ty;
    for (; e + 24 < e1; e += 32) {
        int s0 = ecol[e], s1 = ecol[e + 8], s2 = ecol[e + 16], s3 = ecol[e + 24];
        float w0 = ecoef[e], w1 = ecoef[e + 8], w2 = ecoef[e + 16], w3 = ecoef[e + 24];
        const float4 v0 = *(const float4*)&r[(size_t)s0 * 128 + c];
        const float4 v1 = *(const float4*)&r[(size_t)s1 * 128 + c];
        const float4 v2 = *(const float4*)&r[(size_t)s2 * 128 + c];
        const float4 v3 = *(const float4*)&r[(size_t)s3 * 128 + c];
        acc.x += v0.x * w0 + v1.x * w1 + v2.x * w2 + v3.x * w3;
        acc.y += v0.y * w0 + v1.y * w1 + v2.y * w2 + v3.y * w3;
        acc.z += v0.z * w0 + v1.z * w1 + v2.z * w2 + v3.z * w3;
        acc.w += v0.w * w0 + v1.w * w1 + v2.w * w2 + v3.w * w3;
    }
    for (; e < e1; e += 8) {
        int s = ecol[e];
        float w = ecoef[e];
        const float4 v = *(const float4*)&r[(size_t)s * 128 + c];
        acc.x += v.x * w; acc.y += v.y * w; acc.z += v.z * w; acc.w += v.w * w;
    }

    __shared__ float red[8][128];
    *(float4*)&red[ty][c] = acc;
    __syncthreads();
    if (tid < 128) {
        float s = 0.0f;
#pragma unroll
        for (int t = 0; t < 8; ++t) s += red[t][tid];
        float inv = (cnt > 0) ? 1.0f / (float)cnt : 0.0f;
        Y[(size_t)g * 128 + tid] = s * inv;
    }
    if (tid == 0) cntf[g] = (float)cnt;
}

extern "C" void kernel_launch(void* const* d_in, const int* in_sizes, int n_in,
                              void* d_out, int out_size, void* d_ws, size_t ws_size,
                              hipStream_t stream) {
    const float* x     = (const float*)d_in[0];
    const int*   ei    = (const int*)d_in[1];
    const int*   batch = (const int*)d_in[2];
    const float* W1    = (const float*)d_in[3];
    const float* b1    = (const float*)d_in[4];
    const float* W2    = (const float*)d_in[5];
    const float* b2    = (const float*)d_in[6];
    const float* W3    = (const float*)d_in[7];
    const float* b3    = (const float*)d_in[8];
    const float* fc1W  = (const float*)d_in[9];
    const float* fc1b  = (const float*)d_in[10];
    const float* fc2W  = (const float*)d_in[11];
    const float* fc2b  = (const float*)d_in[12];
    float* out = (float*)d_out;

    const int* srcp = ei;        // edge_index[0]
    const int* dstp = ei + EE;   // edge_index[1]

    // workspace layout (~75 MB)
    float* r      = (float*)d_ws;                  // N*128
    float* Y      = r + (size_t)NN * 128;          // G*128
    float* pooled = Y + (size_t)GG * 128;          // G*256
    float* cntf   = pooled + (size_t)GG * 256;     // G
    float* dinv   = cntf + GG;                     // N
    float* zbuf   = dinv + NN;                     // N
    float* ecoef  = zbuf + NN;                     // E
    int* indeg  = (int*)(ecoef + EE);              // N
    int* rowptr = indeg + NN;                      // N+4
    int* cursor = rowptr + NN + 4;                 // N
    int* ecol   = cursor + NN;                     // E
    int* bsum   = ecol + EE;                       // 512
    int* boff   = bsum + 512;                      // 513
    int* gstart = boff + 516;                      // G+1

    // CSR build (+ dinv, gstart folded into scan_a)
    hipMemsetAsync(indeg, 0, NN * sizeof(int), stream);
    k_count<<<EE / 256, 256, 0, stream>>>(dstp, indeg);
    k_scan_a<<<NN / 256, 256, 0, stream>>>(indeg, bsum, dinv, batch, gstart);
    k_scan_b<<<1, 512, 0, stream>>>(bsum, boff);
    k_scan_c<<<NN / 256, 256, 0, stream>>>(indeg, boff, rowptr, cursor);
    k_fill_edges<<<EE / 256, 256, 0, stream>>>(srcp, dstp, dinv, cursor, ecol, ecoef);

    // conv1 scalar
    k_z<<<NN / 256, 256, 0, stream>>>(x, dinv, rowptr, ecol, ecoef, zbuf);

    // conv2 fused: r = relu([Â relu(z⊗W1+b1)] @ W2 + b2)
    k_gemm2u<<<NN / 64, 256, 0, stream>>>(zbuf, dinv, rowptr, ecol, ecoef,
                                          W1, b1, W2, b2, r);

    // conv3 aggregation + mean pool
    k_pool<<<GG, 256, 0, stream>>>(r, dinv, rowptr, ecol, ecoef, gstart, Y, cntf);

    // head: pooled = Y@W3+b3 (guarded), then fused fc1+fc2
    k_gemm<128, 256, false, true><<<dim3(GG / 64, 2), 256, 0, stream>>>(
        Y, W3, b3, cntf, pooled);
    k_fc12<<<GG / 64, 256, 0, stream>>>(pooled, fc1W, fc1b, fc2W, fc2b, out);
}

// Round 10
// 147.989 us; speedup vs baseline: 7.1538x; 1.0042x over previous
//
#include <hip/hip_runtime.h>

#define NN 131072   // nodes
#define EE 262144   // edges
#define GG 4096     // graphs

// ---------- custom zero (hipMemsetAsync's fill kernel costs 40us for 512KB) ----------
__global__ void k_zero(int4* __restrict__ p, int n4) {
    int i = blockIdx.x * 256 + threadIdx.x;
    if (i < n4) p[i] = make_int4(0, 0, 0, 0);
}

// ---------- CSR build ----------
__global__ void k_count(const int* __restrict__ dst, int* __restrict__ indeg) {
    int e = blockIdx.x * 256 + threadIdx.x;
    if (e < EE) atomicAdd(&indeg[dst[e]], 1);
}

// A: per-block (256 elems) totals + dinv + gstart from sorted batch
__global__ __launch_bounds__(256) void k_scan_a(const int* __restrict__ indeg,
                                                int* __restrict__ bsum,
                                                float* __restrict__ dinv,
                                                const int* __restrict__ batch,
                                                int* __restrict__ gstart) {
    __shared__ int red[256];
    int tid = threadIdx.x;
    int gid = blockIdx.x * 256 + tid;
    int v = indeg[gid];
    dinv[gid] = rsqrtf((float)v + 1.0f);
    red[tid] = v;
    {
        int b1v = batch[gid];
        int b0v = (gid == 0) ? -1 : batch[gid - 1];
        for (int g = b0v + 1; g <= b1v; ++g) gstart[g] = gid;
        if (gid == NN - 1)
            for (int g = b1v + 1; g <= GG; ++g) gstart[g] = NN;
    }
    __syncthreads();
#pragma unroll
    for (int off = 128; off > 0; off >>= 1) {
        if (tid < off) red[tid] += red[tid + off];
        __syncthreads();
    }
    if (tid == 0) bsum[blockIdx.x] = red[0];
}

// B: single block, exclusive scan of bsum[512] -> boff[513]
__global__ __launch_bounds__(512) void k_scan_b(const int* __restrict__ bsum,
                                                int* __restrict__ boff) {
    __shared__ int ps[512];
    int tid = threadIdx.x;
    ps[tid] = bsum[tid];
    __syncthreads();
    for (int off = 1; off < 512; off <<= 1) {
        int v = (tid >= off) ? ps[tid - off] : 0;
        __syncthreads();
        ps[tid] += v;
        __syncthreads();
    }
    boff[tid] = (tid > 0) ? ps[tid - 1] : 0;
    if (tid == 511) boff[512] = ps[511];
}

// C: per-block local exclusive scan + block offset -> rowptr & cursor
__global__ __launch_bounds__(256) void k_scan_c(const int* __restrict__ indeg,
                                                const int* __restrict__ boff,
                                                int* __restrict__ rowptr,
                                                int* __restrict__ cursor) {
    __shared__ int ps[256];
    int tid = threadIdx.x;
    int gid = blockIdx.x * 256 + tid;
    int v = indeg[gid];
    ps[tid] = v;
    __syncthreads();
    for (int off = 1; off < 256; off <<= 1) {
        int t = (tid >= off) ? ps[tid - off] : 0;
        __syncthreads();
        ps[tid] += t;
        __syncthreads();
    }
    int excl = boff[blockIdx.x] + ps[tid] - v;
    rowptr[gid] = excl;
    cursor[gid] = excl;
    if (gid == NN - 1) rowptr[NN] = boff[512];
}

// fill ecol + per-slot coefficient ecoef = dinv[d]*dinv[s]
__global__ void k_fill_edges(const int* __restrict__ src, const int* __restrict__ dst,
                             const float* __restrict__ dinv,
                             int* __restrict__ cursor, int* __restrict__ ecol,
                             float* __restrict__ ecoef) {
    int e = blockIdx.x * 256 + threadIdx.x;
    if (e < EE) {
        int d = dst[e], s = src[e];
        int slot = atomicAdd(&cursor[d], 1);
        ecol[slot] = s;
        ecoef[slot] = dinv[d] * dinv[s];
    }
}

// ---------- conv1 scalar: z[i] = x_i*dinv_i^2 + sum_e ecoef[e]*x[ecol[e]] ----------
__global__ void k_z(const float* __restrict__ x, const float* __restrict__ dinv,
                    const int* __restrict__ rowptr, const int* __restrict__ ecol,
                    const float* __restrict__ ecoef, float* __restrict__ z) {
    int i = blockIdx.x * 256 + threadIdx.x;
    if (i < NN) {
        float di = dinv[i];
        float s = x[i] * di * di;
        int e0 = rowptr[i], e1 = rowptr[i + 1];
        for (int e = e0; e < e1; ++e) s += ecoef[e] * x[ecol[e]];
        z[i] = s;
    }
}

// ---------- fused conv2: r = relu( [Â relu(z⊗W1+b1)] @ W2 + b2 ) ----------
// LDS ~33.6KB -> 4 blocks/CU.
__global__ __launch_bounds__(256) void k_gemm2u(const float* __restrict__ z,
                                                const float* __restrict__ dinv,
                                                const int* __restrict__ rowptr,
                                                const int* __restrict__ ecol,
                                                const float* __restrict__ ecoef,
                                                const float* __restrict__ W1,
                                                const float* __restrict__ b1,
                                                const float* __restrict__ W2,
                                                const float* __restrict__ b2,
                                                float* __restrict__ r) {
    __shared__ float At[64][65];
    __shared__ float Wt[32][128];
    __shared__ float w1s[64], b1s[64];

    int tid = threadIdx.x;
    int i0 = blockIdx.x * 64;

    if (tid < 64) { w1s[tid] = W1[tid]; b1s[tid] = b1[tid]; }
    __syncthreads();

    {   // generate u rows: 4 threads per node, 16 k's each
        int n = tid >> 2;
        int k0 = (tid & 3) * 16;
        int i = i0 + n;
        float zi = z[i], di = dinv[i];
        float d2 = di * di;
        float uacc[16];
#pragma unroll
        for (int j = 0; j < 16; ++j)
            uacc[j] = d2 * fmaxf(zi * w1s[k0 + j] + b1s[k0 + j], 0.f);
        int e0 = rowptr[i], e1 = rowptr[i + 1];
        for (int e = e0; e < e1; ++e) {
            float w = ecoef[e];
            float zs = z[ecol[e]];
#pragma unroll
            for (int j = 0; j < 16; ++j)
                uacc[j] += w * fmaxf(zs * w1s[k0 + j] + b1s[k0 + j], 0.f);
        }
#pragma unroll
        for (int j = 0; j < 16; ++j) At[n][k0 + j] = uacc[j];
    }

    int colg = tid & 15;
    int rowg = tid >> 4;
    float acc[4][8];
#pragma unroll
    for (int rr = 0; rr < 4; ++rr)
#pragma unroll
        for (int c = 0; c < 8; ++c) acc[rr][c] = 0.0f;

    for (int kc = 0; kc < 2; ++kc) {
        if (kc) __syncthreads();
        {
            int c4 = tid & 31, kk0 = tid >> 5;
#pragma unroll
            for (int p = 0; p < 4; ++p) {
                int kk = kk0 + p * 8;
                *(float4*)&Wt[kk][c4 * 4] =
                    *(const float4*)&W2[(size_t)(kc * 32 + kk) * 128 + c4 * 4];
            }
        }
        __syncthreads();
#pragma unroll 4
        for (int kk = 0; kk < 32; ++kk) {
            float a[4];
#pragma unroll
            for (int rr = 0; rr < 4; ++rr) a[rr] = At[rowg * 4 + rr][kc * 32 + kk];
            const float4 w0 = *(const float4*)&Wt[kk][colg * 4];
            const float4 w1 = *(const float4*)&Wt[kk][64 + colg * 4];
            float w[8] = {w0.x, w0.y, w0.z, w0.w, w1.x, w1.y, w1.z, w1.w};
#pragma unroll
            for (int rr = 0; rr < 4; ++rr)
#pragma unroll
                for (int c = 0; c < 8; ++c) acc[rr][c] += a[rr] * w[c];
        }
    }

#pragma unroll
    for (int rr = 0; rr < 4; ++rr) {
        int i = i0 + rowg * 4 + rr;
#pragma unroll
        for (int h = 0; h < 2; ++h) {
            int j = h * 64 + colg * 4;
            const float4 b = *(const float4*)&b2[j];
            float4 v;
            v.x = fmaxf(acc[rr][h * 4 + 0] + b.x, 0.f);
            v.y = fmaxf(acc[rr][h * 4 + 1] + b.y, 0.f);
            v.z = fmaxf(acc[rr][h * 4 + 2] + b.z, 0.f);
            v.w = fmaxf(acc[rr][h * 4 + 3] + b.w, 0.f);
            *(float4*)&r[(size_t)i * 128 + j] = v;
        }
    }
}

// ---------- generic register-tiled GEMM: C = [relu](A @ W + bias[*flag]) ----------
template <int K, int OUTW, bool RELU_OUT, bool GUARD>
__global__ __launch_bounds__(256) void k_gemm(const float* __restrict__ A,
                                              const float* __restrict__ W,
                                              const float* __restrict__ bias,
                                              const float* __restrict__ cntf,
                                              float* __restrict__ C) {
    __shared__ float At[64][68];
    __shared__ float Wt[64][128];

    int tid  = threadIdx.x;
    int colg = tid & 15;
    int rowg = tid >> 4;
    int i0 = blockIdx.x * 64;
    int j0 = blockIdx.y * 128;

    float acc[4][8];
#pragma unroll
    for (int r = 0; r < 4; ++r)
#pragma unroll
        for (int c = 0; c < 8; ++c) acc[r][c] = 0.0f;

    for (int k0 = 0; k0 < K; k0 += 64) {
        __syncthreads();
        {
            int k4 = tid & 15, r0 = tid >> 4;
#pragma unroll
            for (int p = 0; p < 4; ++p) {
                int r = r0 + p * 16;
                *(float4*)&At[r][k4 * 4] =
                    *(const float4*)&A[(size_t)(i0 + r) * K + k0 + k4 * 4];
            }
        }
        {
            int c4 = tid & 31, kk0 = tid >> 5;
#pragma unroll
            for (int p = 0; p < 8; ++p) {
                int kk = kk0 + p * 8;
                *(float4*)&Wt[kk][c4 * 4] =
                    *(const float4*)&W[(size_t)(k0 + kk) * OUTW + j0 + c4 * 4];
            }
        }
        __syncthreads();
#pragma unroll 4
        for (int kk = 0; kk < 64; ++kk) {
            float a[4];
#pragma unroll
            for (int r = 0; r < 4; ++r) a[r] = At[rowg * 4 + r][kk];
            const float4 w0 = *(const float4*)&Wt[kk][colg * 4];
            const float4 w1 = *(const float4*)&Wt[kk][64 + colg * 4];
            float w[8] = {w0.x, w0.y, w0.z, w0.w, w1.x, w1.y, w1.z, w1.w};
#pragma unroll
            for (int r = 0; r < 4; ++r)
#pragma unroll
                for (int c = 0; c < 8; ++c) acc[r][c] += a[r] * w[c];
        }
    }

#pragma unroll
    for (int r = 0; r < 4; ++r) {
        int i = i0 + rowg * 4 + r;
        float flag = 1.0f;
        if (GUARD) flag = (cntf[i] > 0.0f) ? 1.0f : 0.0f;
#pragma unroll
        for (int h = 0; h < 2; ++h) {
            int j = j0 + h * 64 + colg * 4;
            const float4 b = *(const float4*)&bias[j];
            float4 v;
            v.x = acc[r][h * 4 + 0] + b.x * flag;
            v.y = acc[r][h * 4 + 1] + b.y * flag;
            v.z = acc[r][h * 4 + 2] + b.z * flag;
            v.w = acc[r][h * 4 + 3] + b.w * flag;
            if (RELU_OUT) {
                v.x = fmaxf(v.x, 0.f); v.y = fmaxf(v.y, 0.f);
                v.z = fmaxf(v.z, 0.f); v.w = fmaxf(v.w, 0.f);
            }
            *(float4*)&C[(size_t)i * OUTW + j] = v;
        }
    }
}

// ---------- fused head tail: g1 = relu(pooled @ fc1W + fc1b); out = g1 @ fc2W + fc2b ----------
__global__ __launch_bounds__(256) void k_fc12(const float* __restrict__ A,     // pooled G x 256
                                              const float* __restrict__ W,     // fc1W 256 x 128
                                              const float* __restrict__ bias,  // fc1b
                                              const float* __restrict__ fc2W,  // 128 x 12
                                              const float* __restrict__ fc2b,  // 12
                                              float* __restrict__ out) {
    __shared__ float At[64][68];
    __shared__ float Wt[64][128];    // reused as g1 tile after main loop

    int tid  = threadIdx.x;
    int colg = tid & 15;
    int rowg = tid >> 4;
    int i0 = blockIdx.x * 64;

    float acc[4][8];
#pragma unroll
    for (int r = 0; r < 4; ++r)
#pragma unroll
        for (int c = 0; c < 8; ++c) acc[r][c] = 0.0f;

    for (int k0 = 0; k0 < 256; k0 += 64) {
        __syncthreads();
        {
            int k4 = tid & 15, r0 = tid >> 4;
#pragma unroll
            for (int p = 0; p < 4; ++p) {
                int r = r0 + p * 16;
                *(float4*)&At[r][k4 * 4] =
                    *(const float4*)&A[(size_t)(i0 + r) * 256 + k0 + k4 * 4];
            }
        }
        {
            int c4 = tid & 31, kk0 = tid >> 5;
#pragma unroll
            for (int p = 0; p < 8; ++p) {
                int kk = kk0 + p * 8;
                *(float4*)&Wt[kk][c4 * 4] =
                    *(const float4*)&W[(size_t)(k0 + kk) * 128 + c4 * 4];
            }
        }
        __syncthreads();
#pragma unroll 4
        for (int kk = 0; kk < 64; ++kk) {
            float a[4];
#pragma unroll
            for (int r = 0; r < 4; ++r) a[r] = At[rowg * 4 + r][kk];
            const float4 w0 = *(const float4*)&Wt[kk][colg * 4];
            const float4 w1 = *(const float4*)&Wt[kk][64 + colg * 4];
            float w[8] = {w0.x, w0.y, w0.z, w0.w, w1.x, w1.y, w1.z, w1.w};
#pragma unroll
            for (int r = 0; r < 4; ++r)
#pragma unroll
                for (int c = 0; c < 8; ++c) acc[r][c] += a[r] * w[c];
        }
    }
    __syncthreads();   // done reading Wt; reuse as g1 tile [64][128]
    float* g1s = &Wt[0][0];
    float* w2s = &At[0][0];
    for (int idx = tid; idx < 128 * 12; idx += 256) w2s[idx] = fc2W[idx];

#pragma unroll
    for (int r = 0; r < 4; ++r) {
        int row = rowg * 4 + r;
#pragma unroll
        for (int h = 0; h < 2; ++h) {
            int j = h * 64 + colg * 4;
            const float4 b = *(const float4*)&bias[j];
            float4 v;
            v.x = fmaxf(acc[r][h * 4 + 0] + b.x, 0.f);
            v.y = fmaxf(acc[r][h * 4 + 1] + b.y, 0.f);
            v.z = fmaxf(acc[r][h * 4 + 2] + b.z, 0.f);
            v.w = fmaxf(acc[r][h * 4 + 3] + b.w, 0.f);
            *(float4*)&g1s[row * 128 + j] = v;
        }
    }
    __syncthreads();
    for (int idx = tid; idx < 64 * 12; idx += 256) {
        int row = idx / 12, col = idx % 12;
        float o = fc2b[col];
        const float* gr = &g1s[row * 128];
        for (int k = 0; k < 128; ++k) o += gr[k] * w2s[k * 12 + col];
        out[(size_t)(i0 + row) * 12 + col] = o;
    }
}

// ---------- Y_g = mean_{i in g}(Â r)_i — gstart-indexed flat loops ----------
__global__ __launch_bounds__(256) void k_pool(const float* __restrict__ r,
                                              const float* __restrict__ dinv,
                                              const int* __restrict__ rowptr,
                                              const int* __restrict__ ecol,
                                              const float* __restrict__ ecoef,
                                              const int* __restrict__ gstart,
                                              float* __restrict__ Y,
                                              float* __restrict__ cntf) {
    int g = blockIdx.x, tid = threadIdx.x;
    int lo = gstart[g], hi = gstart[g + 1];
    int cnt = hi - lo;

    int lane = tid & 31, ty = tid >> 5;
    int c = lane * 4;
    float4 acc = {0.f, 0.f, 0.f, 0.f};

    // self terms, unroll x2
    int i = lo + ty;
    for (; i + 8 < hi; i += 16) {
        float d0 = dinv[i], d1 = dinv[i + 8];
        const float4 v0 = *(const float4*)&r[(size_t)i * 128 + c];
        const float4 v1 = *(const float4*)&r[(size_t)(i + 8) * 128 + c];
        float w0 = d0 * d0, w1 = d1 * d1;
        acc.x += v0.x * w0 + v1.x * w1;
        acc.y += v0.y * w0 + v1.y * w1;
        acc.z += v0.z * w0 + v1.z * w1;
        acc.w += v0.w * w0 + v1.w * w1;
    }
    for (; i < hi; i += 8) {
        float di = dinv[i], d2 = di * di;
        const float4 v = *(const float4*)&r[(size_t)i * 128 + c];
        acc.x += v.x * d2; acc.y += v.y * d2; acc.z += v.z * d2; acc.w += v.w * d2;
    }

    // edge terms (contiguous slot range), unroll x4
    int e0 = rowptr[lo], e1 = rowptr[hi];
    int e = e0 + ty;
    for (; e + 24 < e1; e += 32) {
        int s0 = ecol[e], s1 = ecol[e + 8], s2 = ecol[e + 16], s3 = ecol[e + 24];
        float w0 = ecoef[e], w1 = ecoef[e + 8], w2 = ecoef[e + 16], w3 = ecoef[e + 24];
        const float4 v0 = *(const float4*)&r[(size_t)s0 * 128 + c];
        const float4 v1 = *(const float4*)&r[(size_t)s1 * 128 + c];
        const float4 v2 = *(const float4*)&r[(size_t)s2 * 128 + c];
        const float4 v3 = *(const float4*)&r[(size_t)s3 * 128 + c];
        acc.x += v0.x * w0 + v1.x * w1 + v2.x * w2 + v3.x * w3;
        acc.y += v0.y * w0 + v1.y * w1 + v2.y * w2 + v3.y * w3;
        acc.z += v0.z * w0 + v1.z * w1 + v2.z * w2 + v3.z * w3;
        acc.w += v0.w * w0 + v1.w * w1 + v2.w * w2 + v3.w * w3;
    }
    for (; e < e1; e += 8) {
        int s = ecol[e];
        float w = ecoef[e];
        const float4 v = *(const float4*)&r[(size_t)s * 128 + c];
        acc.x += v.x * w; acc.y += v.y * w; acc.z += v.z * w; acc.w += v.w * w;
    }

    __shared__ float red[8][128];
    *(float4*)&red[ty][c] = acc;
    __syncthreads();
    if (tid < 128) {
        float s = 0.0f;
#pragma unroll
        for (int t = 0; t < 8; ++t) s += red[t][tid];
        float inv = (cnt > 0) ? 1.0f / (float)cnt : 0.0f;
        Y[(size_t)g * 128 + tid] = s * inv;
    }
    if (tid == 0) cntf[g] = (float)cnt;
}

extern "C" void kernel_launch(void* const* d_in, const int* in_sizes, int n_in,
                              void* d_out, int out_size, void* d_ws, size_t ws_size,
                              hipStream_t stream) {
    const float* x     = (const float*)d_in[0];
    const int*   ei    = (const int*)d_in[1];
    const int*   batch = (const int*)d_in[2];
    const float* W1    = (const float*)d_in[3];
    const float* b1    = (const float*)d_in[4];
    const float* W2    = (const float*)d_in[5];
    const float* b2    = (const float*)d_in[6];
    const float* W3    = (const float*)d_in[7];
    const float* b3    = (const float*)d_in[8];
    const float* fc1W  = (const float*)d_in[9];
    const float* fc1b  = (const float*)d_in[10];
    const float* fc2W  = (const float*)d_in[11];
    const float* fc2b  = (const float*)d_in[12];
    float* out = (float*)d_out;

    const int* srcp = ei;        // edge_index[0]
    const int* dstp = ei + EE;   // edge_index[1]

    // workspace layout (~75 MB)
    float* r      = (float*)d_ws;                  // N*128
    float* Y      = r + (size_t)NN * 128;          // G*128
    float* pooled = Y + (size_t)GG * 128;          // G*256
    float* cntf   = pooled + (size_t)GG * 256;     // G
    float* dinv   = cntf + GG;                     // N
    float* zbuf   = dinv + NN;                     // N
    float* ecoef  = zbuf + NN;                     // E
    int* indeg  = (int*)(ecoef + EE);              // N
    int* rowptr = indeg + NN;                      // N+4
    int* cursor = rowptr + NN + 4;                 // N
    int* ecol   = cursor + NN;                     // E
    int* bsum   = ecol + EE;                       // 512
    int* boff   = bsum + 512;                      // 513
    int* gstart = boff + 516;                      // G+1

    // CSR build (+ dinv, gstart folded into scan_a)
    k_zero<<<NN / 4 / 256, 256, 0, stream>>>((int4*)indeg, NN / 4);
    k_count<<<EE / 256, 256, 0, stream>>>(dstp, indeg);
    k_scan_a<<<NN / 256, 256, 0, stream>>>(indeg, bsum, dinv, batch, gstart);
    k_scan_b<<<1, 512, 0, stream>>>(bsum, boff);
    k_scan_c<<<NN / 256, 256, 0, stream>>>(indeg, boff, rowptr, cursor);
    k_fill_edges<<<EE / 256, 256, 0, stream>>>(srcp, dstp, dinv, cursor, ecol, ecoef);

    // conv1 scalar
    k_z<<<NN / 256, 256, 0, stream>>>(x, dinv, rowptr, ecol, ecoef, zbuf);

    // conv2 fused: r = relu([Â relu(z⊗W1+b1)] @ W2 + b2)
    k_gemm2u<<<NN / 64, 256, 0, stream>>>(zbuf, dinv, rowptr, ecol, ecoef,
                                          W1, b1, W2, b2, r);

    // conv3 aggregation + mean pool
    k_pool<<<GG, 256, 0, stream>>>(r, dinv, rowptr, ecol, ecoef, gstart, Y, cntf);

    // head: pooled = Y@W3+b3 (guarded), then fused fc1+fc2
    k_gemm<128, 256, false, true><<<dim3(GG / 64, 2), 256, 0, stream>>>(
        Y, W3, b3, cntf, pooled);
    k_fc12<<<GG / 64, 256, 0, stream>>>(pooled, fc1W, fc1b, fc2W, fc2b, out);
}